// Round 5
// baseline (281.410 us; speedup 1.0000x reference)
//
#include <hip/hip_runtime.h>

#define KDIM 4096   // rows of x (= both i and j extents)
#define NDIM 1024   // feature dim
#define ALPHA 0.2f
#define LOG2E 1.4426950408889634f
#define CCH 256     // chunks over sorted rank axis
#define RCH 16      // ranks per chunk
#define PFL 256     // LDS-staged (F1,F2) entries per block

// Sorted-prefix decomposition (exact): sort j by s2 desc (permutation sigma);
// sel(i,j) <=> rank(j) < t_i.
//   h_i = [F1_i*A1[t_i] + F2_i*(A2tot-A2[t_i])] / Z_i
//   Z_i =  F1_i*z1[t_i] + F2_i*(z2tot-z2[t_i])
__device__ __align__(16) float g_s1L[KDIM];
__device__ __align__(16) float g_s2L[KDIM];
__device__ __align__(16) float g_E [2 * KDIM];        // interleaved (E1_j, E2_j)
__device__ __align__(16) float g_F [2 * KDIM];        // interleaved (F1_i, F2_i)
__device__ __align__(16) int   g_t  [KDIM];           // t_i = #{j: s2_j >= -s1_i}
__device__ __align__(16) int   g_sig[KDIM];           // rank -> j
__device__ __align__(16) float g_cs [CCH][2 * NDIM];  // chunk sums   (S1 | S2)
__device__ __align__(16) float g_pre[CCH][2 * NDIM];  // excl. prefix (S1 | S2)
__device__ __align__(16) float g_tot[2 * NDIM];       // column totals
__device__ __align__(16) float g_cz [2 * CCH];        // scalar chunk sums (z1,z2)
__device__ __align__(16) float g_zpre[2 * CCH];       // scalar excl. prefix
__device__ __align__(16) float g_ztot[2];             // scalar totals
__device__ int g_ctr;   // DIY grid-barrier counter; host memsets to 0 pre-launch

// DIY grid barrier: monotonic targets within one launch (256, 512, 768, 1024).
// Deadlock-free: grid == 256 == #CUs and __launch_bounds__(256,1) guarantees
// every block is resident before any spin can starve.
__device__ __forceinline__ void gbarrier(int target){
  __threadfence();
  __syncthreads();
  if (threadIdx.x == 0){
    atomicAdd(&g_ctr, 1);
    while (atomicAdd(&g_ctr, 0) < target) __builtin_amdgcn_s_sleep(2);
  }
  __syncthreads();
  __threadfence();
}

__global__ __launch_bounds__(256, 1) void k_all(const float* __restrict__ x,
                                                const float* __restrict__ w,
                                                float* __restrict__ out){
  __shared__ __align__(16) union {
    float s2s[KDIM];                                    // phase B: 16 KB
    struct { float TL[CCH][32]; float SS[8][32]; } d;   // phase D: 33 KB
    struct {
      int    cnt[RCH + 1], off[RCH + 2], pos[RCH + 1];
      int    ilist[KDIM];                               // 16 KB worst-case safe
      float2 pfl[PFL];
    } e;                                                // phase E: ~19 KB
  } sh;
  __shared__ int   js [RCH];          // persistent C -> E (outside union)
  __shared__ float e1s[RCH], e2s[RCH];
  const int tid = threadIdx.x, lane = tid & 63, wv = tid >> 6;
  const int bid = blockIdx.x;

  // ---- phase A: s1/s2 dots + row-local E/F. 4 rows per wave. ----
  {
    float4 W1r[4], W2r[4];
    #pragma unroll
    for (int q = 0; q < 4; ++q){
      const int o = q * 256 + lane * 4;
      W1r[q] = *(const float4*)(w + o);
      W2r[q] = *(const float4*)(w + NDIM + o);
    }
    const int wgid = bid * 4 + wv;
    #pragma unroll
    for (int rr = 0; rr < 4; ++rr){
      const int row = wgid * 4 + rr;
      const float* xr = x + (size_t)row * NDIM;
      float d1 = 0.f, d2 = 0.f;
      #pragma unroll
      for (int q = 0; q < 4; ++q){
        const float4 X = *(const float4*)(xr + q * 256 + lane * 4);
        d1 = fmaf(X.x, W1r[q].x, fmaf(X.y, W1r[q].y, fmaf(X.z, W1r[q].z, fmaf(X.w, W1r[q].w, d1))));
        d2 = fmaf(X.x, W2r[q].x, fmaf(X.y, W2r[q].y, fmaf(X.z, W2r[q].z, fmaf(X.w, W2r[q].w, d2))));
      }
      #pragma unroll
      for (int m = 32; m >= 1; m >>= 1){
        d1 += __shfl_xor(d1, m, 64);
        d2 += __shfl_xor(d2, m, 64);
      }
      if (lane == 0){
        const float s1 = d1 * LOG2E, s2 = d2 * LOG2E;
        g_s1L[row] = s1;
        g_s2L[row] = s2;
        g_E[2 * row]     = __builtin_amdgcn_exp2f(s2);
        g_E[2 * row + 1] = __builtin_amdgcn_exp2f(ALPHA * s2);
        g_F[2 * row]     = __builtin_amdgcn_exp2f(s1);
        g_F[2 * row + 1] = __builtin_amdgcn_exp2f(ALPHA * s1);
      }
    }
  }
  gbarrier(CCH);

  // ---- phase B: ranks + t_i counts. 32 outputs/block (2 passes of 16). ----
  {
    #pragma unroll
    for (int q = 0; q < 4; ++q)
      ((float4*)sh.s2s)[q * 256 + tid] = ((const float4*)g_s2L)[q * 256 + tid];
    __syncthreads();
    const int grp = tid >> 4, sub = tid & 15;
    #pragma unroll
    for (int pass = 0; pass < 2; ++pass){
      const int o = bid * 32 + pass * 16 + grp;     // 0..8191
      int cnt = 0;
      if (o < KDIM){
        const float val = sh.s2s[o];
        #pragma unroll 4
        for (int m = 0; m < 64; ++m){
          const int q4 = m * 16 + sub;
          const float4 v4 = ((const float4*)sh.s2s)[q4];
          const int j0 = q4 * 4;
          cnt += (v4.x > val || (v4.x == val && (j0    ) < o));
          cnt += (v4.y > val || (v4.y == val && (j0 + 1) < o));
          cnt += (v4.z > val || (v4.z == val && (j0 + 2) < o));
          cnt += (v4.w > val || (v4.w == val && (j0 + 3) < o));
        }
      } else {
        const float thr = -g_s1L[o - KDIM];
        #pragma unroll 4
        for (int m = 0; m < 64; ++m){
          const int q4 = m * 16 + sub;
          const float4 v4 = ((const float4*)sh.s2s)[q4];
          cnt += (v4.x >= thr) + (v4.y >= thr) + (v4.z >= thr) + (v4.w >= thr);
        }
      }
      cnt += __shfl_xor(cnt, 1, 64); cnt += __shfl_xor(cnt, 2, 64);
      cnt += __shfl_xor(cnt, 4, 64); cnt += __shfl_xor(cnt, 8, 64);
      if (sub == 0){
        if (o < KDIM) g_sig[cnt] = o;
        else          g_t[o - KDIM] = cnt;
      }
    }
  }
  gbarrier(2 * CCH);

  // ---- phase C: chunk sums; x rows cached in regs for phase E. ----
  float4 v[RCH];
  {
    const int c = bid;
    if (tid < RCH){
      const int j = g_sig[c * RCH + tid];
      js[tid]  = j;
      const float2 e = *(const float2*)&g_E[2 * j];
      e1s[tid] = e.x;
      e2s[tid] = e.y;
    }
    __syncthreads();
    if (tid == 0){
      float a = 0.f, b = 0.f;
      #pragma unroll
      for (int r = 0; r < RCH; ++r){ a += e1s[r]; b += e2s[r]; }
      g_cz[2 * c] = a; g_cz[2 * c + 1] = b;
    }
    #pragma unroll
    for (int r = 0; r < RCH; ++r)
      v[r] = *(const float4*)(x + (size_t)js[r] * NDIM + tid * 4);
    float4 a1 = {0.f,0.f,0.f,0.f}, a2 = {0.f,0.f,0.f,0.f};
    #pragma unroll
    for (int r = 0; r < RCH; ++r){
      const float e1 = e1s[r], e2 = e2s[r];
      const float4 xv = v[r];
      a1.x = fmaf(e1, xv.x, a1.x); a1.y = fmaf(e1, xv.y, a1.y);
      a1.z = fmaf(e1, xv.z, a1.z); a1.w = fmaf(e1, xv.w, a1.w);
      a2.x = fmaf(e2, xv.x, a2.x); a2.y = fmaf(e2, xv.y, a2.y);
      a2.z = fmaf(e2, xv.z, a2.z); a2.w = fmaf(e2, xv.w, a2.w);
    }
    *(float4*)&g_cs[c][tid * 4]        = a1;
    *(float4*)&g_cs[c][NDIM + tid * 4] = a2;
  }
  gbarrier(3 * CCH);

  // ---- phase D: chunk-scan (blocks 0..63, 32 cols each) + z-scan (block 64). ----
  if (bid < 64){
    const int s = tid >> 5, k2 = tid & 31;
    const int col = bid * 32 + k2;
    float run = 0.f;
    #pragma unroll 8
    for (int m = 0; m < 32; ++m){
      const float vv = g_cs[s * 32 + m][col];
      sh.d.TL[s * 32 + m][k2] = vv;
      run += vv;
    }
    sh.d.SS[s][k2] = run;
    __syncthreads();
    if (s == 0){
      float acc = 0.f;
      #pragma unroll
      for (int t = 0; t < 8; ++t){
        const float vv = sh.d.SS[t][k2];
        sh.d.SS[t][k2] = acc;
        acc += vv;
      }
      g_tot[col] = acc;
    }
    __syncthreads();
    run = sh.d.SS[s][k2];
    #pragma unroll 8
    for (int m = 0; m < 32; ++m){
      g_pre[s * 32 + m][col] = run;
      run += sh.d.TL[s * 32 + m][k2];
    }
  } else if (bid == 64 && tid < 64){
    float v1[4], v2[4];
    #pragma unroll
    for (int q = 0; q < 4; ++q){
      v1[q] = g_cz[2 * (tid * 4 + q)];
      v2[q] = g_cz[2 * (tid * 4 + q) + 1];
    }
    const float s1 = v1[0] + v1[1] + v1[2] + v1[3];
    const float s2 = v2[0] + v2[1] + v2[2] + v2[3];
    float i1 = s1, i2 = s2;
    #pragma unroll
    for (int d = 1; d < 64; d <<= 1){
      const float t1 = __shfl_up(i1, d, 64);
      const float t2 = __shfl_up(i2, d, 64);
      if (tid >= d){ i1 += t1; i2 += t2; }
    }
    float e1 = i1 - s1, e2 = i2 - s2;
    #pragma unroll
    for (int q = 0; q < 4; ++q){
      g_zpre[2 * (tid * 4 + q)]     = e1;
      g_zpre[2 * (tid * 4 + q) + 1] = e2;
      e1 += v1[q]; e2 += v2[q];
    }
    if (tid == 63){ g_ztot[0] = e1; g_ztot[1] = e2; }
  }
  gbarrier(4 * CCH);

  // ---- phase E: in-chunk walk + emit; x rows from register cache. ----
  {
    const int c = bid;
    const bool last = (c == CCH - 1);
    const int nbuck = last ? RCH + 1 : RCH;
    if (tid <= RCH) sh.e.cnt[tid] = 0;
    __syncthreads();
    const int tbase = c * RCH;
    int myr[16];
    #pragma unroll
    for (int q = 0; q < 16; ++q){
      const int i = q * 256 + tid;
      const int t = g_t[i];
      const int r = t - tbase;
      const bool in = (r >= 0) && (r < nbuck);
      myr[q] = in ? r : -1;
      if (in) atomicAdd(&sh.e.cnt[r], 1);
    }
    __syncthreads();
    if (tid == 0){
      int run = 0;
      #pragma unroll
      for (int r = 0; r <= RCH; ++r){
        const int vv = sh.e.cnt[r];
        sh.e.off[r] = run; sh.e.pos[r] = run;
        run += vv;
      }
      sh.e.off[RCH + 1] = run;
    }
    __syncthreads();
    #pragma unroll
    for (int q = 0; q < 16; ++q){
      if (myr[q] >= 0){
        const int i = q * 256 + tid;
        const int p = atomicAdd(&sh.e.pos[myr[q]], 1);
        sh.e.ilist[p] = i;
        if (p < PFL) sh.e.pfl[p] = *(const float2*)&g_F[2 * i];
      }
    }
    __syncthreads();

    float4 a1 = *(const float4*)&g_pre[c][tid * 4];
    float4 a2 = *(const float4*)&g_pre[c][NDIM + tid * 4];
    const float4 t2 = *(const float4*)&g_tot[NDIM + tid * 4];
    float za1 = g_zpre[2 * c], za2 = g_zpre[2 * c + 1];
    const float zt2 = g_ztot[1];

    #pragma unroll
    for (int r = 0; r < RCH; ++r){
      for (int e = sh.e.off[r]; e < sh.e.off[r + 1]; ++e){
        const int i = sh.e.ilist[e];
        float F1, F2;
        if (e < PFL){ const float2 pf = sh.e.pfl[e]; F1 = pf.x; F2 = pf.y; }
        else        { const float2 pf = *(const float2*)&g_F[2 * i]; F1 = pf.x; F2 = pf.y; }
        const float rz = 1.0f / fmaf(F1, za1, F2 * (zt2 - za2));
        float4 h;
        h.x = fmaf(F1, a1.x, F2 * (t2.x - a2.x)) * rz;
        h.y = fmaf(F1, a1.y, F2 * (t2.y - a2.y)) * rz;
        h.z = fmaf(F1, a1.z, F2 * (t2.z - a2.z)) * rz;
        h.w = fmaf(F1, a1.w, F2 * (t2.w - a2.w)) * rz;
        *(float4*)(out + (size_t)i * NDIM + tid * 4) = h;
      }
      const float e1 = e1s[r], e2 = e2s[r];
      za1 += e1; za2 += e2;
      const float4 xv = v[r];
      a1.x = fmaf(e1, xv.x, a1.x); a1.y = fmaf(e1, xv.y, a1.y);
      a1.z = fmaf(e1, xv.z, a1.z); a1.w = fmaf(e1, xv.w, a1.w);
      a2.x = fmaf(e2, xv.x, a2.x); a2.y = fmaf(e2, xv.y, a2.y);
      a2.z = fmaf(e2, xv.z, a2.z); a2.w = fmaf(e2, xv.w, a2.w);
    }
    if (last){
      for (int e = sh.e.off[RCH]; e < sh.e.off[RCH + 1]; ++e){
        const int i = sh.e.ilist[e];
        float F1, F2;
        if (e < PFL){ const float2 pf = sh.e.pfl[e]; F1 = pf.x; F2 = pf.y; }
        else        { const float2 pf = *(const float2*)&g_F[2 * i]; F1 = pf.x; F2 = pf.y; }
        const float rz = 1.0f / fmaf(F1, za1, F2 * (zt2 - za2));
        float4 h;
        h.x = fmaf(F1, a1.x, F2 * (t2.x - a2.x)) * rz;
        h.y = fmaf(F1, a1.y, F2 * (t2.y - a2.y)) * rz;
        h.z = fmaf(F1, a1.z, F2 * (t2.z - a2.z)) * rz;
        h.w = fmaf(F1, a1.w, F2 * (t2.w - a2.w)) * rz;
        *(float4*)(out + (size_t)i * NDIM + tid * 4) = h;
      }
    }
  }
}

extern "C" void kernel_launch(void* const* d_in, const int* in_sizes, int n_in,
                              void* d_out, int out_size, void* d_ws, size_t ws_size,
                              hipStream_t stream){
  const float* x = (const float*)d_in[0];   // f32 (4096x1024)
  const float* w = (const float*)d_in[1];   // f32 (2048)
  float* out = (float*)d_out;               // f32 (4096x1024)
  (void)in_sizes; (void)n_in; (void)out_size; (void)d_ws; (void)ws_size;

  static void* ctr_addr = nullptr;
  if (!ctr_addr) (void)hipGetSymbolAddress(&ctr_addr, HIP_SYMBOL(g_ctr));
  (void)hipMemsetAsync(ctr_addr, 0, sizeof(int), stream);   // barrier epoch reset
  k_all<<<dim3(256), dim3(256), 0, stream>>>(x, w, out);
}

// Round 6
// 281.163 us; speedup vs baseline: 1.0009x; 1.0009x over previous
//
#include <hip/hip_runtime.h>

#define KDIM 4096   // rows of x (= both i and j extents)
#define NDIM 1024   // feature dim
#define ALPHA 0.2f
#define LOG2E 1.4426950408889634f
#define CCH 256     // chunks over sorted rank axis
#define RCH 16      // ranks per chunk
#define PFL 256     // LDS-staged (F1,F2) entries per block

// Sorted-prefix decomposition (exact): sort j by s2 desc (permutation sigma);
// sel(i,j) <=> rank(j) < t_i.
//   h_i = [F1_i*A1[t_i] + F2_i*(A2tot-A2[t_i])] / Z_i
//   Z_i =  F1_i*z1[t_i] + F2_i*(z2tot-z2[t_i])
__device__ __align__(16) float g_s1L[KDIM];
__device__ __align__(16) float g_s2L[KDIM];
__device__ __align__(16) float g_E [2 * KDIM];        // interleaved (E1_j, E2_j)
__device__ __align__(16) float g_F [2 * KDIM];        // interleaved (F1_i, F2_i)
__device__ __align__(16) int   g_t  [KDIM];           // t_i = #{j: s2_j >= -s1_i}
__device__ __align__(16) int   g_sig[KDIM];           // rank -> j
__device__ __align__(16) float g_cs [CCH][2 * NDIM];  // chunk sums   (S1 | S2)
__device__ __align__(16) float g_pre[CCH][2 * NDIM];  // excl. prefix (S1 | S2)
__device__ __align__(16) float g_tot[2 * NDIM];       // column totals
__device__ __align__(16) float g_cz [2 * CCH];        // scalar chunk sums (z1,z2)
__device__ __align__(16) float g_zpre[2 * CCH];       // scalar excl. prefix
__device__ __align__(16) float g_ztot[2];             // scalar totals
__device__ int g_ctr;   // DIY grid-barrier counter; host memsets to 0 pre-launch

// DIY grid barrier (proven in R5: correct, no deadlock). Monotonic targets.
// Deadlock-free: grid == 256 == #CUs, 34 KB LDS -> every block resident.
__device__ __forceinline__ void gbarrier(int target){
  __threadfence();
  __syncthreads();
  if (threadIdx.x == 0){
    atomicAdd(&g_ctr, 1);
    while (atomicAdd(&g_ctr, 0) < target) __builtin_amdgcn_s_sleep(2);
  }
  __syncthreads();
  __threadfence();
}

// R5 post-mortem: NO register state may cross a gbarrier (the float4 v[16]
// cache forced a 64-VGPR live range across two barriers -> allocator capped
// at 60 VGPR -> 32 MB scratch spill -> 230 us). Phase E re-reads x instead
// (L3-resident after phase A: ~2-3 us). Each phase body is verbatim the
// proven round-2 standalone kernel body.
__global__ __launch_bounds__(256) void k_all(const float* __restrict__ x,
                                             const float* __restrict__ w,
                                             float* __restrict__ out){
  __shared__ __align__(16) union {
    float s2s[KDIM];                                    // phase B: 16 KB
    struct { float TL[CCH][32]; float SS[8][32]; } d;   // phase D: 33 KB
    struct {
      int    cnt[RCH + 1], off[RCH + 2], pos[RCH + 1];
      int    ilist[KDIM];                               // 16 KB worst-case safe
      float2 pfl[PFL];
    } e;                                                // phase E: ~19 KB
  } sh;
  __shared__ int   js [RCH];          // persistent C -> E (outside union)
  __shared__ float e1s[RCH], e2s[RCH];
  const int tid = threadIdx.x, lane = tid & 63, wv = tid >> 6;
  const int bid = blockIdx.x;

  // ---- phase A: s1/s2 dots + row-local E/F. 4 rows per wave. ----
  {
    float4 W1r[4], W2r[4];
    #pragma unroll
    for (int q = 0; q < 4; ++q){
      const int o = q * 256 + lane * 4;
      W1r[q] = *(const float4*)(w + o);
      W2r[q] = *(const float4*)(w + NDIM + o);
    }
    const int wgid = bid * 4 + wv;
    #pragma unroll
    for (int rr = 0; rr < 4; ++rr){
      const int row = wgid * 4 + rr;
      const float* xr = x + (size_t)row * NDIM;
      float d1 = 0.f, d2 = 0.f;
      #pragma unroll
      for (int q = 0; q < 4; ++q){
        const float4 X = *(const float4*)(xr + q * 256 + lane * 4);
        d1 = fmaf(X.x, W1r[q].x, fmaf(X.y, W1r[q].y, fmaf(X.z, W1r[q].z, fmaf(X.w, W1r[q].w, d1))));
        d2 = fmaf(X.x, W2r[q].x, fmaf(X.y, W2r[q].y, fmaf(X.z, W2r[q].z, fmaf(X.w, W2r[q].w, d2))));
      }
      #pragma unroll
      for (int m = 32; m >= 1; m >>= 1){
        d1 += __shfl_xor(d1, m, 64);
        d2 += __shfl_xor(d2, m, 64);
      }
      if (lane == 0){
        const float s1 = d1 * LOG2E, s2 = d2 * LOG2E;
        g_s1L[row] = s1;
        g_s2L[row] = s2;
        g_E[2 * row]     = __builtin_amdgcn_exp2f(s2);
        g_E[2 * row + 1] = __builtin_amdgcn_exp2f(ALPHA * s2);
        g_F[2 * row]     = __builtin_amdgcn_exp2f(s1);
        g_F[2 * row + 1] = __builtin_amdgcn_exp2f(ALPHA * s1);
      }
    }
  }
  gbarrier(CCH);

  // ---- phase B: ranks + t_i counts. 32 outputs/block (2 passes of 16). ----
  {
    #pragma unroll
    for (int q = 0; q < 4; ++q)
      ((float4*)sh.s2s)[q * 256 + tid] = ((const float4*)g_s2L)[q * 256 + tid];
    __syncthreads();
    const int grp = tid >> 4, sub = tid & 15;
    #pragma unroll
    for (int pass = 0; pass < 2; ++pass){
      const int o = bid * 32 + pass * 16 + grp;     // 0..8191
      int cnt = 0;
      if (o < KDIM){
        const float val = sh.s2s[o];
        #pragma unroll 4
        for (int m = 0; m < 64; ++m){
          const int q4 = m * 16 + sub;
          const float4 v4 = ((const float4*)sh.s2s)[q4];
          const int j0 = q4 * 4;
          cnt += (v4.x > val || (v4.x == val && (j0    ) < o));
          cnt += (v4.y > val || (v4.y == val && (j0 + 1) < o));
          cnt += (v4.z > val || (v4.z == val && (j0 + 2) < o));
          cnt += (v4.w > val || (v4.w == val && (j0 + 3) < o));
        }
      } else {
        const float thr = -g_s1L[o - KDIM];
        #pragma unroll 4
        for (int m = 0; m < 64; ++m){
          const int q4 = m * 16 + sub;
          const float4 v4 = ((const float4*)sh.s2s)[q4];
          cnt += (v4.x >= thr) + (v4.y >= thr) + (v4.z >= thr) + (v4.w >= thr);
        }
      }
      cnt += __shfl_xor(cnt, 1, 64); cnt += __shfl_xor(cnt, 2, 64);
      cnt += __shfl_xor(cnt, 4, 64); cnt += __shfl_xor(cnt, 8, 64);
      if (sub == 0){
        if (o < KDIM) g_sig[cnt] = o;
        else          g_t[o - KDIM] = cnt;
      }
    }
  }
  gbarrier(2 * CCH);

  // ---- phase C: chunk sums (verbatim round-2 k_chunksum). ----
  {
    const int c = bid;
    if (tid < RCH){
      const int j = g_sig[c * RCH + tid];
      js[tid]  = j;
      const float2 e = *(const float2*)&g_E[2 * j];
      e1s[tid] = e.x;
      e2s[tid] = e.y;
    }
    __syncthreads();
    if (tid == 0){
      float a = 0.f, b = 0.f;
      #pragma unroll
      for (int r = 0; r < RCH; ++r){ a += e1s[r]; b += e2s[r]; }
      g_cz[2 * c] = a; g_cz[2 * c + 1] = b;
    }
    float4 a1 = {0.f,0.f,0.f,0.f}, a2 = {0.f,0.f,0.f,0.f};
    #pragma unroll
    for (int r = 0; r < RCH; ++r){
      const float4 xv = *(const float4*)(x + (size_t)js[r] * NDIM + tid * 4);
      const float e1 = e1s[r], e2 = e2s[r];
      a1.x = fmaf(e1, xv.x, a1.x); a1.y = fmaf(e1, xv.y, a1.y);
      a1.z = fmaf(e1, xv.z, a1.z); a1.w = fmaf(e1, xv.w, a1.w);
      a2.x = fmaf(e2, xv.x, a2.x); a2.y = fmaf(e2, xv.y, a2.y);
      a2.z = fmaf(e2, xv.z, a2.z); a2.w = fmaf(e2, xv.w, a2.w);
    }
    *(float4*)&g_cs[c][tid * 4]        = a1;
    *(float4*)&g_cs[c][NDIM + tid * 4] = a2;
  }
  gbarrier(3 * CCH);

  // ---- phase D: chunk-scan (blocks 0..63, 32 cols each) + z-scan (block 64). ----
  if (bid < 64){
    const int s = tid >> 5, k2 = tid & 31;
    const int col = bid * 32 + k2;
    float run = 0.f;
    #pragma unroll 8
    for (int m = 0; m < 32; ++m){
      const float vv = g_cs[s * 32 + m][col];
      sh.d.TL[s * 32 + m][k2] = vv;
      run += vv;
    }
    sh.d.SS[s][k2] = run;
    __syncthreads();
    if (s == 0){
      float acc = 0.f;
      #pragma unroll
      for (int t = 0; t < 8; ++t){
        const float vv = sh.d.SS[t][k2];
        sh.d.SS[t][k2] = acc;
        acc += vv;
      }
      g_tot[col] = acc;
    }
    __syncthreads();
    run = sh.d.SS[s][k2];
    #pragma unroll 8
    for (int m = 0; m < 32; ++m){
      g_pre[s * 32 + m][col] = run;
      run += sh.d.TL[s * 32 + m][k2];
    }
  } else if (bid == 64 && tid < 64){
    float v1[4], v2[4];
    #pragma unroll
    for (int q = 0; q < 4; ++q){
      v1[q] = g_cz[2 * (tid * 4 + q)];
      v2[q] = g_cz[2 * (tid * 4 + q) + 1];
    }
    const float s1 = v1[0] + v1[1] + v1[2] + v1[3];
    const float s2 = v2[0] + v2[1] + v2[2] + v2[3];
    float i1 = s1, i2 = s2;
    #pragma unroll
    for (int d = 1; d < 64; d <<= 1){
      const float t1 = __shfl_up(i1, d, 64);
      const float t2 = __shfl_up(i2, d, 64);
      if (tid >= d){ i1 += t1; i2 += t2; }
    }
    float e1 = i1 - s1, e2 = i2 - s2;
    #pragma unroll
    for (int q = 0; q < 4; ++q){
      g_zpre[2 * (tid * 4 + q)]     = e1;
      g_zpre[2 * (tid * 4 + q) + 1] = e2;
      e1 += v1[q]; e2 += v2[q];
    }
    if (tid == 63){ g_ztot[0] = e1; g_ztot[1] = e2; }
  }
  gbarrier(4 * CCH);

  // ---- phase E: in-chunk walk + emit (verbatim round-2 k_emit; x re-read,
  //      L3-resident; js/e1s/e2s persist in LDS from phase C). ----
  {
    const int c = bid;
    const bool last = (c == CCH - 1);
    const int nbuck = last ? RCH + 1 : RCH;
    if (tid <= RCH) sh.e.cnt[tid] = 0;
    __syncthreads();
    const int tbase = c * RCH;
    int myr[16];
    #pragma unroll
    for (int q = 0; q < 16; ++q){
      const int i = q * 256 + tid;
      const int t = g_t[i];
      const int r = t - tbase;
      const bool in = (r >= 0) && (r < nbuck);
      myr[q] = in ? r : -1;
      if (in) atomicAdd(&sh.e.cnt[r], 1);
    }
    __syncthreads();
    if (tid == 0){
      int run = 0;
      #pragma unroll
      for (int r = 0; r <= RCH; ++r){
        const int vv = sh.e.cnt[r];
        sh.e.off[r] = run; sh.e.pos[r] = run;
        run += vv;
      }
      sh.e.off[RCH + 1] = run;
    }
    __syncthreads();
    #pragma unroll
    for (int q = 0; q < 16; ++q){
      if (myr[q] >= 0){
        const int i = q * 256 + tid;
        const int p = atomicAdd(&sh.e.pos[myr[q]], 1);
        sh.e.ilist[p] = i;
        if (p < PFL) sh.e.pfl[p] = *(const float2*)&g_F[2 * i];
      }
    }
    __syncthreads();

    float4 a1 = *(const float4*)&g_pre[c][tid * 4];
    float4 a2 = *(const float4*)&g_pre[c][NDIM + tid * 4];
    const float4 t2 = *(const float4*)&g_tot[NDIM + tid * 4];
    float za1 = g_zpre[2 * c], za2 = g_zpre[2 * c + 1];
    const float zt2 = g_ztot[1];
    float4 v[RCH];
    #pragma unroll
    for (int r = 0; r < RCH; ++r)     // phase-local load; L3 hit
      v[r] = *(const float4*)(x + (size_t)js[r] * NDIM + tid * 4);

    #pragma unroll
    for (int r = 0; r < RCH; ++r){
      for (int e = sh.e.off[r]; e < sh.e.off[r + 1]; ++e){
        const int i = sh.e.ilist[e];
        float F1, F2;
        if (e < PFL){ const float2 pf = sh.e.pfl[e]; F1 = pf.x; F2 = pf.y; }
        else        { const float2 pf = *(const float2*)&g_F[2 * i]; F1 = pf.x; F2 = pf.y; }
        const float rz = 1.0f / fmaf(F1, za1, F2 * (zt2 - za2));
        float4 h;
        h.x = fmaf(F1, a1.x, F2 * (t2.x - a2.x)) * rz;
        h.y = fmaf(F1, a1.y, F2 * (t2.y - a2.y)) * rz;
        h.z = fmaf(F1, a1.z, F2 * (t2.z - a2.z)) * rz;
        h.w = fmaf(F1, a1.w, F2 * (t2.w - a2.w)) * rz;
        *(float4*)(out + (size_t)i * NDIM + tid * 4) = h;
      }
      const float e1 = e1s[r], e2 = e2s[r];
      za1 += e1; za2 += e2;
      const float4 xv = v[r];
      a1.x = fmaf(e1, xv.x, a1.x); a1.y = fmaf(e1, xv.y, a1.y);
      a1.z = fmaf(e1, xv.z, a1.z); a1.w = fmaf(e1, xv.w, a1.w);
      a2.x = fmaf(e2, xv.x, a2.x); a2.y = fmaf(e2, xv.y, a2.y);
      a2.z = fmaf(e2, xv.z, a2.z); a2.w = fmaf(e2, xv.w, a2.w);
    }
    if (last){
      for (int e = sh.e.off[RCH]; e < sh.e.off[RCH + 1]; ++e){
        const int i = sh.e.ilist[e];
        float F1, F2;
        if (e < PFL){ const float2 pf = sh.e.pfl[e]; F1 = pf.x; F2 = pf.y; }
        else        { const float2 pf = *(const float2*)&g_F[2 * i]; F1 = pf.x; F2 = pf.y; }
        const float rz = 1.0f / fmaf(F1, za1, F2 * (zt2 - za2));
        float4 h;
        h.x = fmaf(F1, a1.x, F2 * (t2.x - a2.x)) * rz;
        h.y = fmaf(F1, a1.y, F2 * (t2.y - a2.y)) * rz;
        h.z = fmaf(F1, a1.z, F2 * (t2.z - a2.z)) * rz;
        h.w = fmaf(F1, a1.w, F2 * (t2.w - a2.w)) * rz;
        *(float4*)(out + (size_t)i * NDIM + tid * 4) = h;
      }
    }
  }
}

extern "C" void kernel_launch(void* const* d_in, const int* in_sizes, int n_in,
                              void* d_out, int out_size, void* d_ws, size_t ws_size,
                              hipStream_t stream){
  const float* x = (const float*)d_in[0];   // f32 (4096x1024)
  const float* w = (const float*)d_in[1];   // f32 (2048)
  float* out = (float*)d_out;               // f32 (4096x1024)
  (void)in_sizes; (void)n_in; (void)out_size; (void)d_ws; (void)ws_size;

  static void* ctr_addr = nullptr;
  if (!ctr_addr) (void)hipGetSymbolAddress(&ctr_addr, HIP_SYMBOL(g_ctr));
  (void)hipMemsetAsync(ctr_addr, 0, sizeof(int), stream);   // barrier epoch reset
  k_all<<<dim3(256), dim3(256), 0, stream>>>(x, w, out);
}

// Round 7
// 154.678 us; speedup vs baseline: 1.8193x; 1.8177x over previous
//
#include <hip/hip_runtime.h>

#define KDIM 4096   // rows of x (= both i and j extents)
#define NDIM 1024   // feature dim
#define ALPHA 0.2f
#define LOG2E 1.4426950408889634f
#define CCH 256     // chunks over sorted rank axis
#define RCH 16      // ranks per chunk
#define PFL 256     // LDS-staged (F1,F2) entries per block

// Sorted-prefix decomposition (exact): sort j by s2 desc (permutation sigma);
// sel(i,j) <=> rank(j) < t_i.
//   h_i = [F1_i*A1[t_i] + F2_i*(A2tot-A2[t_i])] / Z_i
//   Z_i =  F1_i*z1[t_i] + F2_i*(z2tot-z2[t_i])
__device__ __align__(16) float g_s1L[KDIM];
__device__ __align__(16) float g_s2L[KDIM];
__device__ __align__(16) float g_E [2 * KDIM];        // interleaved (E1_j, E2_j)
__device__ __align__(16) float g_F [2 * KDIM];        // interleaved (F1_i, F2_i)
__device__ __align__(16) int   g_t  [KDIM];           // t_i = #{j: s2_j >= -s1_i}
__device__ __align__(16) int   g_sig[KDIM];           // rank -> j
__device__ __align__(16) float g_cs [CCH][2 * NDIM];  // chunk sums   (S1 | S2)
__device__ __align__(16) float g_pre[CCH][2 * NDIM];  // excl. prefix (S1 | S2)
__device__ __align__(16) float g_tot[2 * NDIM];       // column totals
__device__ __align__(16) float g_cz [2 * CCH];        // scalar chunk sums (z1,z2)
__device__ __align__(16) float g_zpre[2 * CCH];       // scalar excl. prefix
__device__ __align__(16) float g_ztot[2];             // scalar totals
__device__ __align__(8) int g_bar[2];   // [0]=arrival ctr, [1]=epoch flag (host zeroes)

// Grid barrier v2 (R6 post-mortem: RMW-poll storm was ~50us/barrier).
// Arrival: ONE relaxed agent-scope fetch_add per block (pipelined at the
// coherence point). Release: last arriver stores epoch flag. Wait: relaxed
// agent-scope LOADS (read-only; no same-address RMW serialization, no
// per-poll buffer_inv). One explicit release/acquire "agent" fence per
// barrier handles cross-XCD L2 visibility.
__device__ __forceinline__ void gbarrier(int epoch){
  __syncthreads();
  if (threadIdx.x == 0){
    __builtin_amdgcn_fence(__ATOMIC_RELEASE, "agent");   // publish our stores
    const int old = __hip_atomic_fetch_add(&g_bar[0], 1, __ATOMIC_RELAXED,
                                           __HIP_MEMORY_SCOPE_AGENT);
    if (old == epoch * 256 - 1){
      __hip_atomic_store(&g_bar[1], epoch, __ATOMIC_RELAXED,
                         __HIP_MEMORY_SCOPE_AGENT);
    } else {
      while (__hip_atomic_load(&g_bar[1], __ATOMIC_RELAXED,
                               __HIP_MEMORY_SCOPE_AGENT) < epoch)
        __builtin_amdgcn_s_sleep(8);
    }
    __builtin_amdgcn_fence(__ATOMIC_ACQUIRE, "agent");   // see others' stores
  }
  __syncthreads();
}

__global__ __launch_bounds__(256) void k_all(const float* __restrict__ x,
                                             const float* __restrict__ w,
                                             float* __restrict__ out){
  __shared__ __align__(16) union {
    float s2s[KDIM];                                    // phase B: 16 KB
    struct { float TL[CCH][32]; float SS[8][32]; } d;   // phase D: 33 KB
    struct {
      int    cnt[RCH + 1], off[RCH + 2], pos[RCH + 1];
      int    ilist[KDIM];                               // 16 KB worst-case safe
      float2 pfl[PFL];
    } e;                                                // phase E: ~19 KB
  } sh;
  __shared__ int   js [RCH];          // persistent C -> E (outside union)
  __shared__ float e1s[RCH], e2s[RCH];
  const int tid = threadIdx.x, lane = tid & 63, wv = tid >> 6;
  const int bid = blockIdx.x;

  // ---- phase A: s1/s2 dots + row-local E/F. 4 rows per wave. ----
  {
    float4 W1r[4], W2r[4];
    #pragma unroll
    for (int q = 0; q < 4; ++q){
      const int o = q * 256 + lane * 4;
      W1r[q] = *(const float4*)(w + o);
      W2r[q] = *(const float4*)(w + NDIM + o);
    }
    const int wgid = bid * 4 + wv;
    #pragma unroll
    for (int rr = 0; rr < 4; ++rr){
      const int row = wgid * 4 + rr;
      const float* xr = x + (size_t)row * NDIM;
      float d1 = 0.f, d2 = 0.f;
      #pragma unroll
      for (int q = 0; q < 4; ++q){
        const float4 X = *(const float4*)(xr + q * 256 + lane * 4);
        d1 = fmaf(X.x, W1r[q].x, fmaf(X.y, W1r[q].y, fmaf(X.z, W1r[q].z, fmaf(X.w, W1r[q].w, d1))));
        d2 = fmaf(X.x, W2r[q].x, fmaf(X.y, W2r[q].y, fmaf(X.z, W2r[q].z, fmaf(X.w, W2r[q].w, d2))));
      }
      #pragma unroll
      for (int m = 32; m >= 1; m >>= 1){
        d1 += __shfl_xor(d1, m, 64);
        d2 += __shfl_xor(d2, m, 64);
      }
      if (lane == 0){
        const float s1 = d1 * LOG2E, s2 = d2 * LOG2E;
        g_s1L[row] = s1;
        g_s2L[row] = s2;
        g_E[2 * row]     = __builtin_amdgcn_exp2f(s2);
        g_E[2 * row + 1] = __builtin_amdgcn_exp2f(ALPHA * s2);
        g_F[2 * row]     = __builtin_amdgcn_exp2f(s1);
        g_F[2 * row + 1] = __builtin_amdgcn_exp2f(ALPHA * s1);
      }
    }
  }
  gbarrier(1);

  // ---- phase B: ranks + t_i counts. 32 outputs/block (2 passes of 16). ----
  {
    #pragma unroll
    for (int q = 0; q < 4; ++q)
      ((float4*)sh.s2s)[q * 256 + tid] = ((const float4*)g_s2L)[q * 256 + tid];
    __syncthreads();
    const int grp = tid >> 4, sub = tid & 15;
    #pragma unroll
    for (int pass = 0; pass < 2; ++pass){
      const int o = bid * 32 + pass * 16 + grp;     // 0..8191
      int cnt = 0;
      if (o < KDIM){
        const float val = sh.s2s[o];
        #pragma unroll 4
        for (int m = 0; m < 64; ++m){
          const int q4 = m * 16 + sub;
          const float4 v4 = ((const float4*)sh.s2s)[q4];
          const int j0 = q4 * 4;
          cnt += (v4.x > val || (v4.x == val && (j0    ) < o));
          cnt += (v4.y > val || (v4.y == val && (j0 + 1) < o));
          cnt += (v4.z > val || (v4.z == val && (j0 + 2) < o));
          cnt += (v4.w > val || (v4.w == val && (j0 + 3) < o));
        }
      } else {
        const float thr = -g_s1L[o - KDIM];
        #pragma unroll 4
        for (int m = 0; m < 64; ++m){
          const int q4 = m * 16 + sub;
          const float4 v4 = ((const float4*)sh.s2s)[q4];
          cnt += (v4.x >= thr) + (v4.y >= thr) + (v4.z >= thr) + (v4.w >= thr);
        }
      }
      cnt += __shfl_xor(cnt, 1, 64); cnt += __shfl_xor(cnt, 2, 64);
      cnt += __shfl_xor(cnt, 4, 64); cnt += __shfl_xor(cnt, 8, 64);
      if (sub == 0){
        if (o < KDIM) g_sig[cnt] = o;
        else          g_t[o - KDIM] = cnt;
      }
    }
  }
  gbarrier(2);

  // ---- phase C: chunk sums (verbatim round-2 k_chunksum). ----
  {
    const int c = bid;
    if (tid < RCH){
      const int j = g_sig[c * RCH + tid];
      js[tid]  = j;
      const float2 e = *(const float2*)&g_E[2 * j];
      e1s[tid] = e.x;
      e2s[tid] = e.y;
    }
    __syncthreads();
    if (tid == 0){
      float a = 0.f, b = 0.f;
      #pragma unroll
      for (int r = 0; r < RCH; ++r){ a += e1s[r]; b += e2s[r]; }
      g_cz[2 * c] = a; g_cz[2 * c + 1] = b;
    }
    float4 a1 = {0.f,0.f,0.f,0.f}, a2 = {0.f,0.f,0.f,0.f};
    #pragma unroll
    for (int r = 0; r < RCH; ++r){
      const float4 xv = *(const float4*)(x + (size_t)js[r] * NDIM + tid * 4);
      const float e1 = e1s[r], e2 = e2s[r];
      a1.x = fmaf(e1, xv.x, a1.x); a1.y = fmaf(e1, xv.y, a1.y);
      a1.z = fmaf(e1, xv.z, a1.z); a1.w = fmaf(e1, xv.w, a1.w);
      a2.x = fmaf(e2, xv.x, a2.x); a2.y = fmaf(e2, xv.y, a2.y);
      a2.z = fmaf(e2, xv.z, a2.z); a2.w = fmaf(e2, xv.w, a2.w);
    }
    *(float4*)&g_cs[c][tid * 4]        = a1;
    *(float4*)&g_cs[c][NDIM + tid * 4] = a2;
  }
  gbarrier(3);

  // ---- phase D: chunk-scan (blocks 0..63, 32 cols each) + z-scan (block 64). ----
  if (bid < 64){
    const int s = tid >> 5, k2 = tid & 31;
    const int col = bid * 32 + k2;
    float run = 0.f;
    #pragma unroll 8
    for (int m = 0; m < 32; ++m){
      const float vv = g_cs[s * 32 + m][col];
      sh.d.TL[s * 32 + m][k2] = vv;
      run += vv;
    }
    sh.d.SS[s][k2] = run;
    __syncthreads();
    if (s == 0){
      float acc = 0.f;
      #pragma unroll
      for (int t = 0; t < 8; ++t){
        const float vv = sh.d.SS[t][k2];
        sh.d.SS[t][k2] = acc;
        acc += vv;
      }
      g_tot[col] = acc;
    }
    __syncthreads();
    run = sh.d.SS[s][k2];
    #pragma unroll 8
    for (int m = 0; m < 32; ++m){
      g_pre[s * 32 + m][col] = run;
      run += sh.d.TL[s * 32 + m][k2];
    }
  } else if (bid == 64 && tid < 64){
    float v1[4], v2[4];
    #pragma unroll
    for (int q = 0; q < 4; ++q){
      v1[q] = g_cz[2 * (tid * 4 + q)];
      v2[q] = g_cz[2 * (tid * 4 + q) + 1];
    }
    const float s1 = v1[0] + v1[1] + v1[2] + v1[3];
    const float s2 = v2[0] + v2[1] + v2[2] + v2[3];
    float i1 = s1, i2 = s2;
    #pragma unroll
    for (int d = 1; d < 64; d <<= 1){
      const float t1 = __shfl_up(i1, d, 64);
      const float t2 = __shfl_up(i2, d, 64);
      if (tid >= d){ i1 += t1; i2 += t2; }
    }
    float e1 = i1 - s1, e2 = i2 - s2;
    #pragma unroll
    for (int q = 0; q < 4; ++q){
      g_zpre[2 * (tid * 4 + q)]     = e1;
      g_zpre[2 * (tid * 4 + q) + 1] = e2;
      e1 += v1[q]; e2 += v2[q];
    }
    if (tid == 63){ g_ztot[0] = e1; g_ztot[1] = e2; }
  }
  gbarrier(4);

  // ---- phase E: in-chunk walk + emit (x re-read, L2/L3-resident;
  //      js/e1s/e2s persist in LDS from phase C). ----
  {
    const int c = bid;
    const bool last = (c == CCH - 1);
    const int nbuck = last ? RCH + 1 : RCH;
    if (tid <= RCH) sh.e.cnt[tid] = 0;
    __syncthreads();
    const int tbase = c * RCH;
    int myr[16];
    #pragma unroll
    for (int q = 0; q < 16; ++q){
      const int i = q * 256 + tid;
      const int t = g_t[i];
      const int r = t - tbase;
      const bool in = (r >= 0) && (r < nbuck);
      myr[q] = in ? r : -1;
      if (in) atomicAdd(&sh.e.cnt[r], 1);
    }
    __syncthreads();
    if (tid == 0){
      int run = 0;
      #pragma unroll
      for (int r = 0; r <= RCH; ++r){
        const int vv = sh.e.cnt[r];
        sh.e.off[r] = run; sh.e.pos[r] = run;
        run += vv;
      }
      sh.e.off[RCH + 1] = run;
    }
    __syncthreads();
    #pragma unroll
    for (int q = 0; q < 16; ++q){
      if (myr[q] >= 0){
        const int i = q * 256 + tid;
        const int p = atomicAdd(&sh.e.pos[myr[q]], 1);
        sh.e.ilist[p] = i;
        if (p < PFL) sh.e.pfl[p] = *(const float2*)&g_F[2 * i];
      }
    }
    __syncthreads();

    float4 a1 = *(const float4*)&g_pre[c][tid * 4];
    float4 a2 = *(const float4*)&g_pre[c][NDIM + tid * 4];
    const float4 t2 = *(const float4*)&g_tot[NDIM + tid * 4];
    float za1 = g_zpre[2 * c], za2 = g_zpre[2 * c + 1];
    const float zt2 = g_ztot[1];
    float4 v[RCH];
    #pragma unroll
    for (int r = 0; r < RCH; ++r)     // phase-local load; cache hit
      v[r] = *(const float4*)(x + (size_t)js[r] * NDIM + tid * 4);

    #pragma unroll
    for (int r = 0; r < RCH; ++r){
      for (int e = sh.e.off[r]; e < sh.e.off[r + 1]; ++e){
        const int i = sh.e.ilist[e];
        float F1, F2;
        if (e < PFL){ const float2 pf = sh.e.pfl[e]; F1 = pf.x; F2 = pf.y; }
        else        { const float2 pf = *(const float2*)&g_F[2 * i]; F1 = pf.x; F2 = pf.y; }
        const float rz = 1.0f / fmaf(F1, za1, F2 * (zt2 - za2));
        float4 h;
        h.x = fmaf(F1, a1.x, F2 * (t2.x - a2.x)) * rz;
        h.y = fmaf(F1, a1.y, F2 * (t2.y - a2.y)) * rz;
        h.z = fmaf(F1, a1.z, F2 * (t2.z - a2.z)) * rz;
        h.w = fmaf(F1, a1.w, F2 * (t2.w - a2.w)) * rz;
        *(float4*)(out + (size_t)i * NDIM + tid * 4) = h;
      }
      const float e1 = e1s[r], e2 = e2s[r];
      za1 += e1; za2 += e2;
      const float4 xv = v[r];
      a1.x = fmaf(e1, xv.x, a1.x); a1.y = fmaf(e1, xv.y, a1.y);
      a1.z = fmaf(e1, xv.z, a1.z); a1.w = fmaf(e1, xv.w, a1.w);
      a2.x = fmaf(e2, xv.x, a2.x); a2.y = fmaf(e2, xv.y, a2.y);
      a2.z = fmaf(e2, xv.z, a2.z); a2.w = fmaf(e2, xv.w, a2.w);
    }
    if (last){
      for (int e = sh.e.off[RCH]; e < sh.e.off[RCH + 1]; ++e){
        const int i = sh.e.ilist[e];
        float F1, F2;
        if (e < PFL){ const float2 pf = sh.e.pfl[e]; F1 = pf.x; F2 = pf.y; }
        else        { const float2 pf = *(const float2*)&g_F[2 * i]; F1 = pf.x; F2 = pf.y; }
        const float rz = 1.0f / fmaf(F1, za1, F2 * (zt2 - za2));
        float4 h;
        h.x = fmaf(F1, a1.x, F2 * (t2.x - a2.x)) * rz;
        h.y = fmaf(F1, a1.y, F2 * (t2.y - a2.y)) * rz;
        h.z = fmaf(F1, a1.z, F2 * (t2.z - a2.z)) * rz;
        h.w = fmaf(F1, a1.w, F2 * (t2.w - a2.w)) * rz;
        *(float4*)(out + (size_t)i * NDIM + tid * 4) = h;
      }
    }
  }
}

extern "C" void kernel_launch(void* const* d_in, const int* in_sizes, int n_in,
                              void* d_out, int out_size, void* d_ws, size_t ws_size,
                              hipStream_t stream){
  const float* x = (const float*)d_in[0];   // f32 (4096x1024)
  const float* w = (const float*)d_in[1];   // f32 (2048)
  float* out = (float*)d_out;               // f32 (4096x1024)
  (void)in_sizes; (void)n_in; (void)out_size; (void)d_ws; (void)ws_size;

  static void* bar_addr = nullptr;
  if (!bar_addr) (void)hipGetSymbolAddress(&bar_addr, HIP_SYMBOL(g_bar));
  (void)hipMemsetAsync(bar_addr, 0, 2 * sizeof(int), stream);  // epoch reset
  k_all<<<dim3(256), dim3(256), 0, stream>>>(x, w, out);
}

// Round 8
// 134.263 us; speedup vs baseline: 2.0960x; 1.1521x over previous
//
#include <hip/hip_runtime.h>

#define KDIM 4096   // rows of x (= both i and j extents)
#define NDIM 1024   // feature dim
#define ALPHA 0.2f
#define LOG2E 1.4426950408889634f
#define CCH 256     // chunks over sorted rank axis
#define RCH 16      // ranks per chunk
#define PFL 256     // LDS-staged (F1,F2) entries per block

// Sorted-prefix decomposition (exact): sort j by s2 desc (permutation sigma);
// sel(i,j) <=> rank(j) < t_i.
//   h_i = [F1_i*A1[t_i] + F2_i*(A2tot-A2[t_i])] / Z_i
//   Z_i =  F1_i*z1[t_i] + F2_i*(z2tot-z2[t_i])
__device__ __align__(16) float g_s1L[KDIM];
__device__ __align__(16) float g_s2L[KDIM];
__device__ __align__(16) float g_E [2 * KDIM];        // interleaved (E1_j, E2_j)
__device__ __align__(16) float g_F [2 * KDIM];        // interleaved (F1_i, F2_i)
__device__ __align__(16) int   g_t  [KDIM];           // t_i = #{j: s2_j >= -s1_i}
__device__ __align__(16) int   g_sig[KDIM];           // rank -> j
__device__ __align__(16) float g_cs [CCH][2 * NDIM];  // chunk sums   (S1 | S2)
__device__ __align__(16) float g_pre[CCH][2 * NDIM];  // excl. prefix (S1 | S2)
__device__ __align__(16) float g_tot[2 * NDIM];       // column totals
__device__ __align__(16) float g_cz [2 * CCH];        // scalar chunk sums (z1,z2)
__device__ __align__(16) float g_zpre[2 * CCH];       // scalar excl. prefix
__device__ __align__(16) float g_ztot[2];             // scalar totals
// barrier v3 state: 256 padded arrival slots (16B each) + flag. Host zeroes.
__device__ __align__(16) int g_sync[256 * 4 + 4];     // [bid*4]=slot, [1024]=flag

// Grid barrier v3 — ZERO RMW (R7 post-mortem: 256 same-line fetch_adds from
// 8 XCDs serialize ~200cyc each = ~21us/barrier; R6: RMW *polling* was ~50us).
// Arrival: relaxed agent store to per-block padded slot (no serialization).
// Detect: block 0's 256 threads poll one slot each concurrently (~1us sweep).
// Publish: single flag store; others poll flag with read-only loads (cheap,
// proven in R7). Monotonic epochs; no slot reuse hazard (flag gates progress).
// Deadlock-free: 256 blocks = 256 CUs, 34 KB LDS -> all co-resident.
__device__ __forceinline__ void gbarrier(int epoch){
  __syncthreads();
  const int tid = threadIdx.x, bid = blockIdx.x;
  if (tid == 0){
    __builtin_amdgcn_fence(__ATOMIC_RELEASE, "agent");      // publish our stores
    __hip_atomic_store(&g_sync[bid * 4], epoch, __ATOMIC_RELAXED,
                       __HIP_MEMORY_SCOPE_AGENT);
  }
  if (bid == 0){
    while (__hip_atomic_load(&g_sync[tid * 4], __ATOMIC_RELAXED,
                             __HIP_MEMORY_SCOPE_AGENT) < epoch)
      __builtin_amdgcn_s_sleep(4);
    __syncthreads();                                         // all slots seen
    if (tid == 0)
      __hip_atomic_store(&g_sync[1024], epoch, __ATOMIC_RELAXED,
                         __HIP_MEMORY_SCOPE_AGENT);
  } else if (tid == 0){
    while (__hip_atomic_load(&g_sync[1024], __ATOMIC_RELAXED,
                             __HIP_MEMORY_SCOPE_AGENT) < epoch)
      __builtin_amdgcn_s_sleep(8);
  }
  if (tid == 0)
    __builtin_amdgcn_fence(__ATOMIC_ACQUIRE, "agent");       // see others' stores
  __syncthreads();
}

__global__ __launch_bounds__(256) void k_all(const float* __restrict__ x,
                                             const float* __restrict__ w,
                                             float* __restrict__ out){
  __shared__ __align__(16) union {
    float s2s[KDIM];                                    // phase B: 16 KB
    struct { float TL[CCH][32]; float SS[8][32]; } d;   // phase D: 33 KB
    struct {
      int    cnt[RCH + 1], off[RCH + 2], pos[RCH + 1];
      int    ilist[KDIM];                               // 16 KB worst-case safe
      float2 pfl[PFL];
    } e;                                                // phase E: ~19 KB
  } sh;
  __shared__ int   js [RCH];          // persistent C -> E (outside union)
  __shared__ float e1s[RCH], e2s[RCH];
  const int tid = threadIdx.x, lane = tid & 63, wv = tid >> 6;
  const int bid = blockIdx.x;

  // ---- phase A: s1/s2 dots + row-local E/F. 4 rows per wave. ----
  {
    float4 W1r[4], W2r[4];
    #pragma unroll
    for (int q = 0; q < 4; ++q){
      const int o = q * 256 + lane * 4;
      W1r[q] = *(const float4*)(w + o);
      W2r[q] = *(const float4*)(w + NDIM + o);
    }
    const int wgid = bid * 4 + wv;
    #pragma unroll
    for (int rr = 0; rr < 4; ++rr){
      const int row = wgid * 4 + rr;
      const float* xr = x + (size_t)row * NDIM;
      float d1 = 0.f, d2 = 0.f;
      #pragma unroll
      for (int q = 0; q < 4; ++q){
        const float4 X = *(const float4*)(xr + q * 256 + lane * 4);
        d1 = fmaf(X.x, W1r[q].x, fmaf(X.y, W1r[q].y, fmaf(X.z, W1r[q].z, fmaf(X.w, W1r[q].w, d1))));
        d2 = fmaf(X.x, W2r[q].x, fmaf(X.y, W2r[q].y, fmaf(X.z, W2r[q].z, fmaf(X.w, W2r[q].w, d2))));
      }
      #pragma unroll
      for (int m = 32; m >= 1; m >>= 1){
        d1 += __shfl_xor(d1, m, 64);
        d2 += __shfl_xor(d2, m, 64);
      }
      if (lane == 0){
        const float s1 = d1 * LOG2E, s2 = d2 * LOG2E;
        g_s1L[row] = s1;
        g_s2L[row] = s2;
        g_E[2 * row]     = __builtin_amdgcn_exp2f(s2);
        g_E[2 * row + 1] = __builtin_amdgcn_exp2f(ALPHA * s2);
        g_F[2 * row]     = __builtin_amdgcn_exp2f(s1);
        g_F[2 * row + 1] = __builtin_amdgcn_exp2f(ALPHA * s1);
      }
    }
  }
  gbarrier(1);

  // ---- phase B: ranks + t_i counts. 32 outputs/block (2 passes of 16). ----
  {
    #pragma unroll
    for (int q = 0; q < 4; ++q)
      ((float4*)sh.s2s)[q * 256 + tid] = ((const float4*)g_s2L)[q * 256 + tid];
    __syncthreads();
    const int grp = tid >> 4, sub = tid & 15;
    #pragma unroll
    for (int pass = 0; pass < 2; ++pass){
      const int o = bid * 32 + pass * 16 + grp;     // 0..8191
      int cnt = 0;
      if (o < KDIM){
        const float val = sh.s2s[o];
        #pragma unroll 4
        for (int m = 0; m < 64; ++m){
          const int q4 = m * 16 + sub;
          const float4 v4 = ((const float4*)sh.s2s)[q4];
          const int j0 = q4 * 4;
          cnt += (v4.x > val || (v4.x == val && (j0    ) < o));
          cnt += (v4.y > val || (v4.y == val && (j0 + 1) < o));
          cnt += (v4.z > val || (v4.z == val && (j0 + 2) < o));
          cnt += (v4.w > val || (v4.w == val && (j0 + 3) < o));
        }
      } else {
        const float thr = -g_s1L[o - KDIM];
        #pragma unroll 4
        for (int m = 0; m < 64; ++m){
          const int q4 = m * 16 + sub;
          const float4 v4 = ((const float4*)sh.s2s)[q4];
          cnt += (v4.x >= thr) + (v4.y >= thr) + (v4.z >= thr) + (v4.w >= thr);
        }
      }
      cnt += __shfl_xor(cnt, 1, 64); cnt += __shfl_xor(cnt, 2, 64);
      cnt += __shfl_xor(cnt, 4, 64); cnt += __shfl_xor(cnt, 8, 64);
      if (sub == 0){
        if (o < KDIM) g_sig[cnt] = o;
        else          g_t[o - KDIM] = cnt;
      }
    }
  }
  gbarrier(2);

  // ---- phase C: chunk sums (verbatim round-2 k_chunksum). ----
  {
    const int c = bid;
    if (tid < RCH){
      const int j = g_sig[c * RCH + tid];
      js[tid]  = j;
      const float2 e = *(const float2*)&g_E[2 * j];
      e1s[tid] = e.x;
      e2s[tid] = e.y;
    }
    __syncthreads();
    if (tid == 0){
      float a = 0.f, b = 0.f;
      #pragma unroll
      for (int r = 0; r < RCH; ++r){ a += e1s[r]; b += e2s[r]; }
      g_cz[2 * c] = a; g_cz[2 * c + 1] = b;
    }
    float4 a1 = {0.f,0.f,0.f,0.f}, a2 = {0.f,0.f,0.f,0.f};
    #pragma unroll
    for (int r = 0; r < RCH; ++r){
      const float4 xv = *(const float4*)(x + (size_t)js[r] * NDIM + tid * 4);
      const float e1 = e1s[r], e2 = e2s[r];
      a1.x = fmaf(e1, xv.x, a1.x); a1.y = fmaf(e1, xv.y, a1.y);
      a1.z = fmaf(e1, xv.z, a1.z); a1.w = fmaf(e1, xv.w, a1.w);
      a2.x = fmaf(e2, xv.x, a2.x); a2.y = fmaf(e2, xv.y, a2.y);
      a2.z = fmaf(e2, xv.z, a2.z); a2.w = fmaf(e2, xv.w, a2.w);
    }
    *(float4*)&g_cs[c][tid * 4]        = a1;
    *(float4*)&g_cs[c][NDIM + tid * 4] = a2;
  }
  gbarrier(3);

  // ---- phase D: chunk-scan (blocks 0..63, 32 cols each) + z-scan (block 64). ----
  if (bid < 64){
    const int s = tid >> 5, k2 = tid & 31;
    const int col = bid * 32 + k2;
    float run = 0.f;
    #pragma unroll 8
    for (int m = 0; m < 32; ++m){
      const float vv = g_cs[s * 32 + m][col];
      sh.d.TL[s * 32 + m][k2] = vv;
      run += vv;
    }
    sh.d.SS[s][k2] = run;
    __syncthreads();
    if (s == 0){
      float acc = 0.f;
      #pragma unroll
      for (int t = 0; t < 8; ++t){
        const float vv = sh.d.SS[t][k2];
        sh.d.SS[t][k2] = acc;
        acc += vv;
      }
      g_tot[col] = acc;
    }
    __syncthreads();
    run = sh.d.SS[s][k2];
    #pragma unroll 8
    for (int m = 0; m < 32; ++m){
      g_pre[s * 32 + m][col] = run;
      run += sh.d.TL[s * 32 + m][k2];
    }
  } else if (bid == 64 && tid < 64){
    float v1[4], v2[4];
    #pragma unroll
    for (int q = 0; q < 4; ++q){
      v1[q] = g_cz[2 * (tid * 4 + q)];
      v2[q] = g_cz[2 * (tid * 4 + q) + 1];
    }
    const float s1 = v1[0] + v1[1] + v1[2] + v1[3];
    const float s2 = v2[0] + v2[1] + v2[2] + v2[3];
    float i1 = s1, i2 = s2;
    #pragma unroll
    for (int d = 1; d < 64; d <<= 1){
      const float t1 = __shfl_up(i1, d, 64);
      const float t2 = __shfl_up(i2, d, 64);
      if (tid >= d){ i1 += t1; i2 += t2; }
    }
    float e1 = i1 - s1, e2 = i2 - s2;
    #pragma unroll
    for (int q = 0; q < 4; ++q){
      g_zpre[2 * (tid * 4 + q)]     = e1;
      g_zpre[2 * (tid * 4 + q) + 1] = e2;
      e1 += v1[q]; e2 += v2[q];
    }
    if (tid == 63){ g_ztot[0] = e1; g_ztot[1] = e2; }
  }
  gbarrier(4);

  // ---- phase E: in-chunk walk + emit (x re-read, cache-resident;
  //      js/e1s/e2s persist in LDS from phase C). ----
  {
    const int c = bid;
    const bool last = (c == CCH - 1);
    const int nbuck = last ? RCH + 1 : RCH;
    if (tid <= RCH) sh.e.cnt[tid] = 0;
    __syncthreads();
    const int tbase = c * RCH;
    int myr[16];
    #pragma unroll
    for (int q = 0; q < 16; ++q){
      const int i = q * 256 + tid;
      const int t = g_t[i];
      const int r = t - tbase;
      const bool in = (r >= 0) && (r < nbuck);
      myr[q] = in ? r : -1;
      if (in) atomicAdd(&sh.e.cnt[r], 1);
    }
    __syncthreads();
    if (tid == 0){
      int run = 0;
      #pragma unroll
      for (int r = 0; r <= RCH; ++r){
        const int vv = sh.e.cnt[r];
        sh.e.off[r] = run; sh.e.pos[r] = run;
        run += vv;
      }
      sh.e.off[RCH + 1] = run;
    }
    __syncthreads();
    #pragma unroll
    for (int q = 0; q < 16; ++q){
      if (myr[q] >= 0){
        const int i = q * 256 + tid;
        const int p = atomicAdd(&sh.e.pos[myr[q]], 1);
        sh.e.ilist[p] = i;
        if (p < PFL) sh.e.pfl[p] = *(const float2*)&g_F[2 * i];
      }
    }
    __syncthreads();

    float4 a1 = *(const float4*)&g_pre[c][tid * 4];
    float4 a2 = *(const float4*)&g_pre[c][NDIM + tid * 4];
    const float4 t2 = *(const float4*)&g_tot[NDIM + tid * 4];
    float za1 = g_zpre[2 * c], za2 = g_zpre[2 * c + 1];
    const float zt2 = g_ztot[1];
    float4 v[RCH];
    #pragma unroll
    for (int r = 0; r < RCH; ++r)     // phase-local load; cache hit
      v[r] = *(const float4*)(x + (size_t)js[r] * NDIM + tid * 4);

    #pragma unroll
    for (int r = 0; r < RCH; ++r){
      for (int e = sh.e.off[r]; e < sh.e.off[r + 1]; ++e){
        const int i = sh.e.ilist[e];
        float F1, F2;
        if (e < PFL){ const float2 pf = sh.e.pfl[e]; F1 = pf.x; F2 = pf.y; }
        else        { const float2 pf = *(const float2*)&g_F[2 * i]; F1 = pf.x; F2 = pf.y; }
        const float rz = 1.0f / fmaf(F1, za1, F2 * (zt2 - za2));
        float4 h;
        h.x = fmaf(F1, a1.x, F2 * (t2.x - a2.x)) * rz;
        h.y = fmaf(F1, a1.y, F2 * (t2.y - a2.y)) * rz;
        h.z = fmaf(F1, a1.z, F2 * (t2.z - a2.z)) * rz;
        h.w = fmaf(F1, a1.w, F2 * (t2.w - a2.w)) * rz;
        *(float4*)(out + (size_t)i * NDIM + tid * 4) = h;
      }
      const float e1 = e1s[r], e2 = e2s[r];
      za1 += e1; za2 += e2;
      const float4 xv = v[r];
      a1.x = fmaf(e1, xv.x, a1.x); a1.y = fmaf(e1, xv.y, a1.y);
      a1.z = fmaf(e1, xv.z, a1.z); a1.w = fmaf(e1, xv.w, a1.w);
      a2.x = fmaf(e2, xv.x, a2.x); a2.y = fmaf(e2, xv.y, a2.y);
      a2.z = fmaf(e2, xv.z, a2.z); a2.w = fmaf(e2, xv.w, a2.w);
    }
    if (last){
      for (int e = sh.e.off[RCH]; e < sh.e.off[RCH + 1]; ++e){
        const int i = sh.e.ilist[e];
        float F1, F2;
        if (e < PFL){ const float2 pf = sh.e.pfl[e]; F1 = pf.x; F2 = pf.y; }
        else        { const float2 pf = *(const float2*)&g_F[2 * i]; F1 = pf.x; F2 = pf.y; }
        const float rz = 1.0f / fmaf(F1, za1, F2 * (zt2 - za2));
        float4 h;
        h.x = fmaf(F1, a1.x, F2 * (t2.x - a2.x)) * rz;
        h.y = fmaf(F1, a1.y, F2 * (t2.y - a2.y)) * rz;
        h.z = fmaf(F1, a1.z, F2 * (t2.z - a2.z)) * rz;
        h.w = fmaf(F1, a1.w, F2 * (t2.w - a2.w)) * rz;
        *(float4*)(out + (size_t)i * NDIM + tid * 4) = h;
      }
    }
  }
}

extern "C" void kernel_launch(void* const* d_in, const int* in_sizes, int n_in,
                              void* d_out, int out_size, void* d_ws, size_t ws_size,
                              hipStream_t stream){
  const float* x = (const float*)d_in[0];   // f32 (4096x1024)
  const float* w = (const float*)d_in[1];   // f32 (2048)
  float* out = (float*)d_out;               // f32 (4096x1024)
  (void)in_sizes; (void)n_in; (void)out_size; (void)d_ws; (void)ws_size;

  static void* sync_addr = nullptr;
  if (!sync_addr) (void)hipGetSymbolAddress(&sync_addr, HIP_SYMBOL(g_sync));
  (void)hipMemsetAsync(sync_addr, 0, (256 * 4 + 4) * sizeof(int), stream);
  k_all<<<dim3(256), dim3(256), 0, stream>>>(x, w, out);
}

// Round 9
// 119.328 us; speedup vs baseline: 2.3583x; 1.1252x over previous
//
#include <hip/hip_runtime.h>

#define KDIM 4096   // rows of x (= both i and j extents)
#define NDIM 1024   // feature dim
#define ALPHA 0.2f
#define LOG2E 1.4426950408889634f
#define CCH 256     // chunks over sorted rank axis
#define RCH 16      // ranks per chunk
#define PFL 256     // LDS-staged (F1,F2) entries per block

// Sorted-prefix decomposition (exact): sort j by s2 desc (permutation sigma);
// sel(i,j) <=> rank(j) < t_i.
//   h_i = [F1_i*A1[t_i] + F2_i*(A2tot-A2[t_i])] / Z_i
//   Z_i =  F1_i*z1[t_i] + F2_i*(z2tot-z2[t_i])
// ALL cross-phase buffers are accessed ONLY via relaxed agent-scope atomics
// (LLC-coherent, per-access sc1) so the grid barrier needs NO cache fences
// (R8 post-mortem: fence(agent) = buffer_wbl2/buffer_inv = ~15us/barrier and
// evicts the 16MB read-only x from L2 every phase).
__device__ __align__(16) float g_s1L[KDIM];
__device__ __align__(16) float g_s2L[KDIM];
__device__ __align__(16) float g_E [2 * KDIM];        // interleaved (E1_j, E2_j)
__device__ __align__(16) float g_F [2 * KDIM];        // interleaved (F1_i, F2_i)
__device__ __align__(16) int   g_t  [KDIM];           // t_i = #{j: s2_j >= -s1_i}
__device__ __align__(16) int   g_sig[KDIM];           // rank -> j
__device__ __align__(16) float g_cs [CCH][2 * NDIM];  // chunk sums   (S1 | S2)
__device__ __align__(16) float g_pre[CCH][2 * NDIM];  // excl. prefix (S1 | S2)
__device__ __align__(16) float g_tot[2 * NDIM];       // column totals
__device__ __align__(16) float g_cz [2 * CCH];        // scalar chunk sums (z1,z2)
__device__ __align__(16) float g_zpre[2 * CCH];       // scalar excl. prefix
__device__ __align__(16) float g_ztot[2];             // scalar totals
// barrier state: 256 padded arrival slots (16B each) + flag. Host zeroes.
__device__ __align__(16) int g_sync[256 * 4 + 4];     // [bid*4]=slot, [1024]=flag

// ---- relaxed agent-scope atomic access helpers (LLC-coherent, no fences) ----
__device__ __forceinline__ void ast8(float* p, float a, float b){
  float2 v = make_float2(a, b);
  unsigned long long u; __builtin_memcpy(&u, &v, 8);
  __hip_atomic_store((unsigned long long*)p, u, __ATOMIC_RELAXED,
                     __HIP_MEMORY_SCOPE_AGENT);
}
__device__ __forceinline__ float2 ald8(const float* p){
  unsigned long long u = __hip_atomic_load((const unsigned long long*)p,
                                           __ATOMIC_RELAXED, __HIP_MEMORY_SCOPE_AGENT);
  float2 v; __builtin_memcpy(&v, &u, 8); return v;
}
__device__ __forceinline__ void ast4f(float* p, float v){
  int u; __builtin_memcpy(&u, &v, 4);
  __hip_atomic_store((int*)p, u, __ATOMIC_RELAXED, __HIP_MEMORY_SCOPE_AGENT);
}
__device__ __forceinline__ float ald4f(const float* p){
  int u = __hip_atomic_load((const int*)p, __ATOMIC_RELAXED, __HIP_MEMORY_SCOPE_AGENT);
  float v; __builtin_memcpy(&v, &u, 4); return v;
}
__device__ __forceinline__ void ast4i(int* p, int v){
  __hip_atomic_store(p, v, __ATOMIC_RELAXED, __HIP_MEMORY_SCOPE_AGENT);
}
__device__ __forceinline__ int ald4i(const int* p){
  return __hip_atomic_load(p, __ATOMIC_RELAXED, __HIP_MEMORY_SCOPE_AGENT);
}

// Grid barrier v4 — NO fences, NO RMW. All cross-phase data is atomic-agent
// (already at LLC when vmcnt drains). __syncthreads() at entry drains all
// the block's memory ops (compiler emits s_waitcnt before s_barrier), so the
// arrival store is ordered after the data. Consumers' loads issue only after
// the flag is observed -> they read LLC-current values. Detect: block 0's
// 256 threads poll one slot each; publish: single flag store; others poll
// flag with read-only loads. Deadlock-free: 256 blocks = 256 CUs.
__device__ __forceinline__ void gbarrier(int epoch){
  __syncthreads();
  const int tid = threadIdx.x, bid = blockIdx.x;
  if (tid == 0){
    asm volatile("s_waitcnt vmcnt(0) lgkmcnt(0)" ::: "memory");
    __hip_atomic_store(&g_sync[bid * 4], epoch, __ATOMIC_RELAXED,
                       __HIP_MEMORY_SCOPE_AGENT);
  }
  if (bid == 0){
    while (__hip_atomic_load(&g_sync[tid * 4], __ATOMIC_RELAXED,
                             __HIP_MEMORY_SCOPE_AGENT) < epoch)
      __builtin_amdgcn_s_sleep(4);
    __syncthreads();                                         // all slots seen
    if (tid == 0)
      __hip_atomic_store(&g_sync[1024], epoch, __ATOMIC_RELAXED,
                         __HIP_MEMORY_SCOPE_AGENT);
  } else if (tid == 0){
    while (__hip_atomic_load(&g_sync[1024], __ATOMIC_RELAXED,
                             __HIP_MEMORY_SCOPE_AGENT) < epoch)
      __builtin_amdgcn_s_sleep(8);
  }
  __syncthreads();
}

__global__ __launch_bounds__(256) void k_all(const float* __restrict__ x,
                                             const float* __restrict__ w,
                                             float* __restrict__ out){
  __shared__ __align__(16) union {
    float s2s[KDIM];                                    // phase B: 16 KB
    struct { float TL[CCH][32]; float SS[8][32]; } d;   // phase D: 33 KB
    struct {
      int    cnt[RCH + 1], off[RCH + 2], pos[RCH + 1];
      int    ilist[KDIM];                               // 16 KB worst-case safe
      float2 pfl[PFL];
    } e;                                                // phase E: ~19 KB
  } sh;
  __shared__ int   js [RCH];          // persistent C -> E (outside union)
  __shared__ float e1s[RCH], e2s[RCH];
  const int tid = threadIdx.x, lane = tid & 63, wv = tid >> 6;
  const int bid = blockIdx.x;

  // ---- phase A: s1/s2 dots + row-local E/F. 4 rows per wave. ----
  {
    float4 W1r[4], W2r[4];
    #pragma unroll
    for (int q = 0; q < 4; ++q){
      const int o = q * 256 + lane * 4;
      W1r[q] = *(const float4*)(w + o);
      W2r[q] = *(const float4*)(w + NDIM + o);
    }
    const int wgid = bid * 4 + wv;
    #pragma unroll
    for (int rr = 0; rr < 4; ++rr){
      const int row = wgid * 4 + rr;
      const float* xr = x + (size_t)row * NDIM;
      float d1 = 0.f, d2 = 0.f;
      #pragma unroll
      for (int q = 0; q < 4; ++q){
        const float4 X = *(const float4*)(xr + q * 256 + lane * 4);
        d1 = fmaf(X.x, W1r[q].x, fmaf(X.y, W1r[q].y, fmaf(X.z, W1r[q].z, fmaf(X.w, W1r[q].w, d1))));
        d2 = fmaf(X.x, W2r[q].x, fmaf(X.y, W2r[q].y, fmaf(X.z, W2r[q].z, fmaf(X.w, W2r[q].w, d2))));
      }
      #pragma unroll
      for (int m = 32; m >= 1; m >>= 1){
        d1 += __shfl_xor(d1, m, 64);
        d2 += __shfl_xor(d2, m, 64);
      }
      if (lane == 0){
        const float s1 = d1 * LOG2E, s2 = d2 * LOG2E;
        ast4f(&g_s1L[row], s1);
        ast4f(&g_s2L[row], s2);
        ast8(&g_E[2 * row], __builtin_amdgcn_exp2f(s2),
                            __builtin_amdgcn_exp2f(ALPHA * s2));
        ast8(&g_F[2 * row], __builtin_amdgcn_exp2f(s1),
                            __builtin_amdgcn_exp2f(ALPHA * s1));
      }
    }
  }
  gbarrier(1);

  // ---- phase B: ranks + t_i counts. 32 outputs/block (2 passes of 16). ----
  {
    #pragma unroll
    for (int q = 0; q < 8; ++q){
      const float2 v2 = ald8(&g_s2L[(q * 256 + tid) * 2]);
      ((float2*)sh.s2s)[q * 256 + tid] = v2;
    }
    __syncthreads();
    const int grp = tid >> 4, sub = tid & 15;
    #pragma unroll
    for (int pass = 0; pass < 2; ++pass){
      const int o = bid * 32 + pass * 16 + grp;     // 0..8191
      int cnt = 0;
      if (o < KDIM){
        const float val = sh.s2s[o];
        #pragma unroll 4
        for (int m = 0; m < 64; ++m){
          const int q4 = m * 16 + sub;
          const float4 v4 = ((const float4*)sh.s2s)[q4];
          const int j0 = q4 * 4;
          cnt += (v4.x > val || (v4.x == val && (j0    ) < o));
          cnt += (v4.y > val || (v4.y == val && (j0 + 1) < o));
          cnt += (v4.z > val || (v4.z == val && (j0 + 2) < o));
          cnt += (v4.w > val || (v4.w == val && (j0 + 3) < o));
        }
      } else {
        const float thr = -ald4f(&g_s1L[o - KDIM]);
        #pragma unroll 4
        for (int m = 0; m < 64; ++m){
          const int q4 = m * 16 + sub;
          const float4 v4 = ((const float4*)sh.s2s)[q4];
          cnt += (v4.x >= thr) + (v4.y >= thr) + (v4.z >= thr) + (v4.w >= thr);
        }
      }
      cnt += __shfl_xor(cnt, 1, 64); cnt += __shfl_xor(cnt, 2, 64);
      cnt += __shfl_xor(cnt, 4, 64); cnt += __shfl_xor(cnt, 8, 64);
      if (sub == 0){
        if (o < KDIM) ast4i(&g_sig[cnt], o);
        else          ast4i(&g_t[o - KDIM], cnt);
      }
    }
  }
  gbarrier(2);

  // ---- phase C: chunk sums. x reads stay plain (read-only, L2-warm). ----
  {
    const int c = bid;
    if (tid < RCH){
      const int j = ald4i(&g_sig[c * RCH + tid]);
      js[tid]  = j;
      const float2 e = ald8(&g_E[2 * j]);
      e1s[tid] = e.x;
      e2s[tid] = e.y;
    }
    __syncthreads();
    if (tid == 0){
      float a = 0.f, b = 0.f;
      #pragma unroll
      for (int r = 0; r < RCH; ++r){ a += e1s[r]; b += e2s[r]; }
      ast8(&g_cz[2 * c], a, b);
    }
    float4 a1 = {0.f,0.f,0.f,0.f}, a2 = {0.f,0.f,0.f,0.f};
    #pragma unroll
    for (int r = 0; r < RCH; ++r){
      const float4 xv = *(const float4*)(x + (size_t)js[r] * NDIM + tid * 4);
      const float e1 = e1s[r], e2 = e2s[r];
      a1.x = fmaf(e1, xv.x, a1.x); a1.y = fmaf(e1, xv.y, a1.y);
      a1.z = fmaf(e1, xv.z, a1.z); a1.w = fmaf(e1, xv.w, a1.w);
      a2.x = fmaf(e2, xv.x, a2.x); a2.y = fmaf(e2, xv.y, a2.y);
      a2.z = fmaf(e2, xv.z, a2.z); a2.w = fmaf(e2, xv.w, a2.w);
    }
    ast8(&g_cs[c][tid * 4],            a1.x, a1.y);
    ast8(&g_cs[c][tid * 4 + 2],        a1.z, a1.w);
    ast8(&g_cs[c][NDIM + tid * 4],     a2.x, a2.y);
    ast8(&g_cs[c][NDIM + tid * 4 + 2], a2.z, a2.w);
  }
  gbarrier(3);

  // ---- phase D: chunk-scan (blocks 0..63, 32 cols each) + z-scan (block 64). ----
  if (bid < 64){
    const int s = tid >> 5, k2 = tid & 31;
    const int col = bid * 32 + k2;
    float run = 0.f;
    #pragma unroll 8
    for (int m = 0; m < 32; ++m){
      const float vv = ald4f(&g_cs[s * 32 + m][col]);
      sh.d.TL[s * 32 + m][k2] = vv;
      run += vv;
    }
    sh.d.SS[s][k2] = run;
    __syncthreads();
    if (s == 0){
      float acc = 0.f;
      #pragma unroll
      for (int t = 0; t < 8; ++t){
        const float vv = sh.d.SS[t][k2];
        sh.d.SS[t][k2] = acc;
        acc += vv;
      }
      ast4f(&g_tot[col], acc);
    }
    __syncthreads();
    run = sh.d.SS[s][k2];
    #pragma unroll 8
    for (int m = 0; m < 32; ++m){
      ast4f(&g_pre[s * 32 + m][col], run);
      run += sh.d.TL[s * 32 + m][k2];
    }
  } else if (bid == 64 && tid < 64){
    float v1[4], v2[4];
    #pragma unroll
    for (int q = 0; q < 4; ++q){
      const float2 e = ald8(&g_cz[2 * (tid * 4 + q)]);
      v1[q] = e.x; v2[q] = e.y;
    }
    const float s1 = v1[0] + v1[1] + v1[2] + v1[3];
    const float s2 = v2[0] + v2[1] + v2[2] + v2[3];
    float i1 = s1, i2 = s2;
    #pragma unroll
    for (int d = 1; d < 64; d <<= 1){
      const float t1 = __shfl_up(i1, d, 64);
      const float t2 = __shfl_up(i2, d, 64);
      if (tid >= d){ i1 += t1; i2 += t2; }
    }
    float e1 = i1 - s1, e2 = i2 - s2;
    #pragma unroll
    for (int q = 0; q < 4; ++q){
      ast8(&g_zpre[2 * (tid * 4 + q)], e1, e2);
      e1 += v1[q]; e2 += v2[q];
    }
    if (tid == 63) ast8(&g_ztot[0], e1, e2);
  }
  gbarrier(4);

  // ---- phase E: in-chunk walk + emit (x re-read, L2-warm — never
  //      invalidated; js/e1s/e2s persist in LDS from phase C). ----
  {
    const int c = bid;
    const bool last = (c == CCH - 1);
    const int nbuck = last ? RCH + 1 : RCH;
    if (tid <= RCH) sh.e.cnt[tid] = 0;
    __syncthreads();
    const int tbase = c * RCH;
    int myr[16];
    #pragma unroll
    for (int q = 0; q < 16; ++q){
      const int i = q * 256 + tid;
      const int t = ald4i(&g_t[i]);
      const int r = t - tbase;
      const bool in = (r >= 0) && (r < nbuck);
      myr[q] = in ? r : -1;
      if (in) atomicAdd(&sh.e.cnt[r], 1);
    }
    __syncthreads();
    if (tid == 0){
      int run = 0;
      #pragma unroll
      for (int r = 0; r <= RCH; ++r){
        const int vv = sh.e.cnt[r];
        sh.e.off[r] = run; sh.e.pos[r] = run;
        run += vv;
      }
      sh.e.off[RCH + 1] = run;
    }
    __syncthreads();
    #pragma unroll
    for (int q = 0; q < 16; ++q){
      if (myr[q] >= 0){
        const int i = q * 256 + tid;
        const int p = atomicAdd(&sh.e.pos[myr[q]], 1);
        sh.e.ilist[p] = i;
        if (p < PFL){
          const float2 pf = ald8(&g_F[2 * i]);
          sh.e.pfl[p] = pf;
        }
      }
    }
    __syncthreads();

    const float2 p1a = ald8(&g_pre[c][tid * 4]);
    const float2 p1b = ald8(&g_pre[c][tid * 4 + 2]);
    const float2 p2a = ald8(&g_pre[c][NDIM + tid * 4]);
    const float2 p2b = ald8(&g_pre[c][NDIM + tid * 4 + 2]);
    float4 a1 = make_float4(p1a.x, p1a.y, p1b.x, p1b.y);
    float4 a2 = make_float4(p2a.x, p2a.y, p2b.x, p2b.y);
    const float2 t2a = ald8(&g_tot[NDIM + tid * 4]);
    const float2 t2b = ald8(&g_tot[NDIM + tid * 4 + 2]);
    const float4 t2 = make_float4(t2a.x, t2a.y, t2b.x, t2b.y);
    const float2 zp = ald8(&g_zpre[2 * c]);
    float za1 = zp.x, za2 = zp.y;
    const float zt2 = ald8(&g_ztot[0]).y;
    float4 v[RCH];
    #pragma unroll
    for (int r = 0; r < RCH; ++r)     // phase-local load; L2 hit
      v[r] = *(const float4*)(x + (size_t)js[r] * NDIM + tid * 4);

    #pragma unroll
    for (int r = 0; r < RCH; ++r){
      for (int e = sh.e.off[r]; e < sh.e.off[r + 1]; ++e){
        const int i = sh.e.ilist[e];
        float F1, F2;
        if (e < PFL){ const float2 pf = sh.e.pfl[e]; F1 = pf.x; F2 = pf.y; }
        else        { const float2 pf = ald8(&g_F[2 * i]); F1 = pf.x; F2 = pf.y; }
        const float rz = 1.0f / fmaf(F1, za1, F2 * (zt2 - za2));
        float4 h;
        h.x = fmaf(F1, a1.x, F2 * (t2.x - a2.x)) * rz;
        h.y = fmaf(F1, a1.y, F2 * (t2.y - a2.y)) * rz;
        h.z = fmaf(F1, a1.z, F2 * (t2.z - a2.z)) * rz;
        h.w = fmaf(F1, a1.w, F2 * (t2.w - a2.w)) * rz;
        *(float4*)(out + (size_t)i * NDIM + tid * 4) = h;
      }
      const float e1 = e1s[r], e2 = e2s[r];
      za1 += e1; za2 += e2;
      const float4 xv = v[r];
      a1.x = fmaf(e1, xv.x, a1.x); a1.y = fmaf(e1, xv.y, a1.y);
      a1.z = fmaf(e1, xv.z, a1.z); a1.w = fmaf(e1, xv.w, a1.w);
      a2.x = fmaf(e2, xv.x, a2.x); a2.y = fmaf(e2, xv.y, a2.y);
      a2.z = fmaf(e2, xv.z, a2.z); a2.w = fmaf(e2, xv.w, a2.w);
    }
    if (last){
      for (int e = sh.e.off[RCH]; e < sh.e.off[RCH + 1]; ++e){
        const int i = sh.e.ilist[e];
        float F1, F2;
        if (e < PFL){ const float2 pf = sh.e.pfl[e]; F1 = pf.x; F2 = pf.y; }
        else        { const float2 pf = ald8(&g_F[2 * i]); F1 = pf.x; F2 = pf.y; }
        const float rz = 1.0f / fmaf(F1, za1, F2 * (zt2 - za2));
        float4 h;
        h.x = fmaf(F1, a1.x, F2 * (t2.x - a2.x)) * rz;
        h.y = fmaf(F1, a1.y, F2 * (t2.y - a2.y)) * rz;
        h.z = fmaf(F1, a1.z, F2 * (t2.z - a2.z)) * rz;
        h.w = fmaf(F1, a1.w, F2 * (t2.w - a2.w)) * rz;
        *(float4*)(out + (size_t)i * NDIM + tid * 4) = h;
      }
    }
  }
}

extern "C" void kernel_launch(void* const* d_in, const int* in_sizes, int n_in,
                              void* d_out, int out_size, void* d_ws, size_t ws_size,
                              hipStream_t stream){
  const float* x = (const float*)d_in[0];   // f32 (4096x1024)
  const float* w = (const float*)d_in[1];   // f32 (2048)
  float* out = (float*)d_out;               // f32 (4096x1024)
  (void)in_sizes; (void)n_in; (void)out_size; (void)d_ws; (void)ws_size;

  static void* sync_addr = nullptr;
  if (!sync_addr) (void)hipGetSymbolAddress(&sync_addr, HIP_SYMBOL(g_sync));
  (void)hipMemsetAsync(sync_addr, 0, (256 * 4 + 4) * sizeof(int), stream);
  k_all<<<dim3(256), dim3(256), 0, stream>>>(x, w, out);
}

// Round 10
// 116.860 us; speedup vs baseline: 2.4081x; 1.0211x over previous
//
#include <hip/hip_runtime.h>

#define KDIM 4096   // rows of x (= both i and j extents)
#define NDIM 1024   // feature dim
#define ALPHA 0.2f
#define LOG2E 1.4426950408889634f
#define CCH 256     // chunks over sorted rank axis
#define RCH 16      // ranks per chunk
#define PFL 256     // LDS-staged (F1,F2) entries per block
#define GRID 1024   // 4 blocks/CU (LDS 34KB*4=136 <= 160KB -> co-resident)

// Sorted-prefix decomposition (exact): sort j by s2 desc (permutation sigma);
// sel(i,j) <=> rank(j) < t_i.
//   h_i = [F1_i*A1[t_i] + F2_i*(A2tot-A2[t_i])] / Z_i
//   Z_i =  F1_i*z1[t_i] + F2_i*(z2tot-z2[t_i])
// Cross-phase buffers accessed ONLY via relaxed agent-scope atomics (LLC-
// coherent) -> grid barrier needs NO cache fences (R8/R9 proven: fence(agent)
// wbl2/inv cost ~15us/barrier and evicted x from L2).
// R9 post-mortem: 1 block/CU = 4 waves/CU = latency-naked (Occupancy 10%).
// This version: 1024 blocks = 4/CU = 16 waves/CU on every data-parallel phase.
__device__ __align__(16) float g_s1L[KDIM];
__device__ __align__(16) float g_s2L[KDIM];
__device__ __align__(16) float g_E [2 * KDIM];        // interleaved (E1_j, E2_j)
__device__ __align__(16) float g_F [2 * KDIM];        // interleaved (F1_i, F2_i)
__device__ __align__(16) int   g_t  [KDIM];           // t_i = #{j: s2_j >= -s1_i}
__device__ __align__(16) int   g_sig[KDIM];           // rank -> j
__device__ __align__(16) float g_cs [CCH][2 * NDIM];  // chunk sums   (S1 | S2)
__device__ __align__(16) float g_pre[CCH][2 * NDIM];  // excl. prefix (S1 | S2)
__device__ __align__(16) float g_tot[2 * NDIM];       // column totals
__device__ __align__(16) float g_cz [2 * CCH];        // scalar chunk sums (z1,z2)
// barrier state: GRID padded arrival slots (16B each) + flag. Host zeroes.
__device__ __align__(16) int g_sync[GRID * 4 + 4];    // [bid*4]=slot, [4096]=flag

// ---- relaxed agent-scope atomic access helpers (LLC-coherent, no fences) ----
__device__ __forceinline__ void ast8(float* p, float a, float b){
  float2 v = make_float2(a, b);
  unsigned long long u; __builtin_memcpy(&u, &v, 8);
  __hip_atomic_store((unsigned long long*)p, u, __ATOMIC_RELAXED,
                     __HIP_MEMORY_SCOPE_AGENT);
}
__device__ __forceinline__ float2 ald8(const float* p){
  unsigned long long u = __hip_atomic_load((const unsigned long long*)p,
                                           __ATOMIC_RELAXED, __HIP_MEMORY_SCOPE_AGENT);
  float2 v; __builtin_memcpy(&v, &u, 8); return v;
}
__device__ __forceinline__ void ast4f(float* p, float v){
  int u; __builtin_memcpy(&u, &v, 4);
  __hip_atomic_store((int*)p, u, __ATOMIC_RELAXED, __HIP_MEMORY_SCOPE_AGENT);
}
__device__ __forceinline__ float ald4f(const float* p){
  int u = __hip_atomic_load((const int*)p, __ATOMIC_RELAXED, __HIP_MEMORY_SCOPE_AGENT);
  float v; __builtin_memcpy(&v, &u, 4); return v;
}
__device__ __forceinline__ void ast4i(int* p, int v){
  __hip_atomic_store(p, v, __ATOMIC_RELAXED, __HIP_MEMORY_SCOPE_AGENT);
}
__device__ __forceinline__ int ald4i(const int* p){
  return __hip_atomic_load(p, __ATOMIC_RELAXED, __HIP_MEMORY_SCOPE_AGENT);
}

// Grid barrier v4 (R9-proven), scaled to 1024 arrivals. No fences, no RMW.
__device__ __forceinline__ void gbarrier(int epoch){
  __syncthreads();
  const int tid = threadIdx.x, bid = blockIdx.x;
  if (tid == 0){
    asm volatile("s_waitcnt vmcnt(0) lgkmcnt(0)" ::: "memory");
    __hip_atomic_store(&g_sync[bid * 4], epoch, __ATOMIC_RELAXED,
                       __HIP_MEMORY_SCOPE_AGENT);
  }
  if (bid == 0){
    #pragma unroll
    for (int s = 0; s < 4; ++s){
      while (__hip_atomic_load(&g_sync[(s * 256 + tid) * 4], __ATOMIC_RELAXED,
                               __HIP_MEMORY_SCOPE_AGENT) < epoch)
        __builtin_amdgcn_s_sleep(4);
    }
    __syncthreads();                                         // all slots seen
    if (tid == 0)
      __hip_atomic_store(&g_sync[GRID * 4], epoch, __ATOMIC_RELAXED,
                         __HIP_MEMORY_SCOPE_AGENT);
  } else if (tid == 0){
    while (__hip_atomic_load(&g_sync[GRID * 4], __ATOMIC_RELAXED,
                             __HIP_MEMORY_SCOPE_AGENT) < epoch)
      __builtin_amdgcn_s_sleep(8);
  }
  __syncthreads();
}

__global__ __launch_bounds__(256) void k_all(const float* __restrict__ x,
                                             const float* __restrict__ w,
                                             float* __restrict__ out){
  __shared__ __align__(16) union {
    float s2s[KDIM];                                    // phase B: 16 KB
    struct { float TL[CCH][32]; float SS[8][32]; } d;   // phase D: 33 KB
    struct {
      int    cnt[RCH + 1], off[RCH + 2], pos[RCH + 1];
      int    ilist[KDIM];                               // 16 KB worst-case safe
      float2 pfl[PFL];
    } e;                                                // phase E: ~18 KB
  } sh;
  __shared__ int    js [RCH];         // persistent C -> E (outside union)
  __shared__ float  e1s[RCH], e2s[RCH];
  __shared__ float4 zred[4];          // phase E z-reduction partials
  const int tid = threadIdx.x, lane = tid & 63, wv = tid >> 6;
  const int bid = blockIdx.x;

  // ---- phase A: s1/s2 dots + row-local E/F. ONE row per wave. ----
  {
    float4 W1r[4], W2r[4];
    #pragma unroll
    for (int q = 0; q < 4; ++q){
      const int o = q * 256 + lane * 4;
      W1r[q] = *(const float4*)(w + o);
      W2r[q] = *(const float4*)(w + NDIM + o);
    }
    const int row = bid * 4 + wv;
    const float* xr = x + (size_t)row * NDIM;
    float d1 = 0.f, d2 = 0.f;
    #pragma unroll
    for (int q = 0; q < 4; ++q){
      const float4 X = *(const float4*)(xr + q * 256 + lane * 4);
      d1 = fmaf(X.x, W1r[q].x, fmaf(X.y, W1r[q].y, fmaf(X.z, W1r[q].z, fmaf(X.w, W1r[q].w, d1))));
      d2 = fmaf(X.x, W2r[q].x, fmaf(X.y, W2r[q].y, fmaf(X.z, W2r[q].z, fmaf(X.w, W2r[q].w, d2))));
    }
    #pragma unroll
    for (int m = 32; m >= 1; m >>= 1){
      d1 += __shfl_xor(d1, m, 64);
      d2 += __shfl_xor(d2, m, 64);
    }
    if (lane == 0){
      const float s1 = d1 * LOG2E, s2 = d2 * LOG2E;
      ast4f(&g_s1L[row], s1);
      ast4f(&g_s2L[row], s2);
      ast8(&g_E[2 * row], __builtin_amdgcn_exp2f(s2),
                          __builtin_amdgcn_exp2f(ALPHA * s2));
      ast8(&g_F[2 * row], __builtin_amdgcn_exp2f(s1),
                          __builtin_amdgcn_exp2f(ALPHA * s1));
    }
  }
  gbarrier(1);

  // ---- phase B: ranks + t_i counts. 8 outputs/block, 32 subranges each. ----
  {
    #pragma unroll
    for (int q = 0; q < 8; ++q){
      const float2 v2 = ald8(&g_s2L[(q * 256 + tid) * 2]);
      ((float2*)sh.s2s)[q * 256 + tid] = v2;
    }
    __syncthreads();
    const int grp = tid >> 5, sub = tid & 31;
    const int o = bid * 8 + grp;                  // 0..8191
    int cnt = 0;
    if (o < KDIM){
      const float val = sh.s2s[o];
      #pragma unroll 4
      for (int m = 0; m < 32; ++m){
        const int q4 = m * 32 + sub;
        const float4 v4 = ((const float4*)sh.s2s)[q4];
        const int j0 = q4 * 4;
        cnt += (v4.x > val || (v4.x == val && (j0    ) < o));
        cnt += (v4.y > val || (v4.y == val && (j0 + 1) < o));
        cnt += (v4.z > val || (v4.z == val && (j0 + 2) < o));
        cnt += (v4.w > val || (v4.w == val && (j0 + 3) < o));
      }
    } else {
      const float thr = -ald4f(&g_s1L[o - KDIM]);
      #pragma unroll 4
      for (int m = 0; m < 32; ++m){
        const int q4 = m * 32 + sub;
        const float4 v4 = ((const float4*)sh.s2s)[q4];
        cnt += (v4.x >= thr) + (v4.y >= thr) + (v4.z >= thr) + (v4.w >= thr);
      }
    }
    cnt += __shfl_xor(cnt, 1, 64);  cnt += __shfl_xor(cnt, 2, 64);
    cnt += __shfl_xor(cnt, 4, 64);  cnt += __shfl_xor(cnt, 8, 64);
    cnt += __shfl_xor(cnt, 16, 64);
    if (sub == 0){
      if (o < KDIM) ast4i(&g_sig[cnt], o);
      else          ast4i(&g_t[o - KDIM], cnt);
    }
  }
  gbarrier(2);

  // ---- phase C: chunk sums. Chunk c = bid>>2; column quarter qt = bid&3. ----
  {
    const int c = bid >> 2, qt = bid & 3;
    if (tid < RCH){
      const int j = ald4i(&g_sig[c * RCH + tid]);
      js[tid]  = j;
      const float2 e = ald8(&g_E[2 * j]);
      e1s[tid] = e.x;
      e2s[tid] = e.y;
    }
    __syncthreads();
    if (qt == 0 && tid == 0){
      float a = 0.f, b = 0.f;
      #pragma unroll
      for (int r = 0; r < RCH; ++r){ a += e1s[r]; b += e2s[r]; }
      ast8(&g_cz[2 * c], a, b);
    }
    const int col = qt * 256 + tid;               // 0..1023
    float a1 = 0.f, a2 = 0.f;
    #pragma unroll
    for (int r = 0; r < RCH; ++r){
      const float xv = x[(size_t)js[r] * NDIM + col];
      a1 = fmaf(e1s[r], xv, a1);
      a2 = fmaf(e2s[r], xv, a2);
    }
    ast4f(&g_cs[c][col], a1);
    ast4f(&g_cs[c][NDIM + col], a2);
  }
  gbarrier(3);

  // ---- phase D: chunk-scan (blocks 0..63, 32 cols each; z-scan moved to E). --
  if (bid < 64){
    const int s = tid >> 5, k2 = tid & 31;
    const int col = bid * 32 + k2;
    float run = 0.f;
    #pragma unroll 8
    for (int m = 0; m < 32; ++m){
      const float vv = ald4f(&g_cs[s * 32 + m][col]);
      sh.d.TL[s * 32 + m][k2] = vv;
      run += vv;
    }
    sh.d.SS[s][k2] = run;
    __syncthreads();
    if (s == 0){
      float acc = 0.f;
      #pragma unroll
      for (int t = 0; t < 8; ++t){
        const float vv = sh.d.SS[t][k2];
        sh.d.SS[t][k2] = acc;
        acc += vv;
      }
      ast4f(&g_tot[col], acc);
    }
    __syncthreads();
    run = sh.d.SS[s][k2];
    #pragma unroll 8
    for (int m = 0; m < 32; ++m){
      ast4f(&g_pre[s * 32 + m][col], run);
      run += sh.d.TL[s * 32 + m][k2];
    }
  }
  gbarrier(4);

  // ---- phase E: z-reduce + in-chunk walk + emit. Chunk c = bid>>2, qt cols. --
  {
    const int c = bid >> 2, qt = bid & 3;
    const bool last = (c == CCH - 1);
    const int nbuck = last ? RCH + 1 : RCH;

    // scalar z prefix/total from g_cz (one chunk per thread, reduce 256)
    const float2 ez = ald8(&g_cz[2 * tid]);
    float zp1 = (tid < c) ? ez.x : 0.f;
    float zp2 = (tid < c) ? ez.y : 0.f;
    float zt2p = ez.y;
    #pragma unroll
    for (int m = 32; m >= 1; m >>= 1){
      zp1  += __shfl_xor(zp1,  m, 64);
      zp2  += __shfl_xor(zp2,  m, 64);
      zt2p += __shfl_xor(zt2p, m, 64);
    }
    if (lane == 0) zred[wv] = make_float4(zp1, zp2, zt2p, 0.f);
    if (tid <= RCH) sh.e.cnt[tid] = 0;
    __syncthreads();
    float za1 = 0.f, za2 = 0.f, zt2 = 0.f;
    #pragma unroll
    for (int w2 = 0; w2 < 4; ++w2){
      za1 += zred[w2].x; za2 += zred[w2].y; zt2 += zred[w2].z;
    }

    const int tbase = c * RCH;
    int myr[16];
    #pragma unroll
    for (int q = 0; q < 16; ++q){
      const int i = q * 256 + tid;
      const int t = ald4i(&g_t[i]);
      const int r = t - tbase;
      const bool in = (r >= 0) && (r < nbuck);
      myr[q] = in ? r : -1;
      if (in) atomicAdd(&sh.e.cnt[r], 1);
    }
    __syncthreads();
    if (tid == 0){
      int run = 0;
      #pragma unroll
      for (int r = 0; r <= RCH; ++r){
        const int vv = sh.e.cnt[r];
        sh.e.off[r] = run; sh.e.pos[r] = run;
        run += vv;
      }
      sh.e.off[RCH + 1] = run;
    }
    __syncthreads();
    #pragma unroll
    for (int q = 0; q < 16; ++q){
      if (myr[q] >= 0){
        const int i = q * 256 + tid;
        const int p = atomicAdd(&sh.e.pos[myr[q]], 1);
        sh.e.ilist[p] = i;
        if (p < PFL){
          const float2 pf = ald8(&g_F[2 * i]);
          sh.e.pfl[p] = pf;
        }
      }
    }
    __syncthreads();

    const int col = qt * 256 + tid;               // 0..1023
    float a1 = ald4f(&g_pre[c][col]);
    float a2 = ald4f(&g_pre[c][NDIM + col]);
    const float t2 = ald4f(&g_tot[NDIM + col]);
    float v[RCH];
    #pragma unroll
    for (int r = 0; r < RCH; ++r)                 // gathered; L2/L3-warm
      v[r] = x[(size_t)js[r] * NDIM + col];

    #pragma unroll
    for (int r = 0; r < RCH; ++r){
      for (int e = sh.e.off[r]; e < sh.e.off[r + 1]; ++e){
        const int i = sh.e.ilist[e];
        float F1, F2;
        if (e < PFL){ const float2 pf = sh.e.pfl[e]; F1 = pf.x; F2 = pf.y; }
        else        { const float2 pf = ald8(&g_F[2 * i]); F1 = pf.x; F2 = pf.y; }
        const float rz = 1.0f / fmaf(F1, za1, F2 * (zt2 - za2));
        out[(size_t)i * NDIM + col] = fmaf(F1, a1, F2 * (t2 - a2)) * rz;
      }
      za1 += e1s[r]; za2 += e2s[r];
      a1 = fmaf(e1s[r], v[r], a1);
      a2 = fmaf(e2s[r], v[r], a2);
    }
    if (last){
      // t = 4096 bucket: after the walk, a1/za1 hold full totals
      for (int e = sh.e.off[RCH]; e < sh.e.off[RCH + 1]; ++e){
        const int i = sh.e.ilist[e];
        float F1, F2;
        if (e < PFL){ const float2 pf = sh.e.pfl[e]; F1 = pf.x; F2 = pf.y; }
        else        { const float2 pf = ald8(&g_F[2 * i]); F1 = pf.x; F2 = pf.y; }
        const float rz = 1.0f / fmaf(F1, za1, F2 * (zt2 - za2));
        out[(size_t)i * NDIM + col] = fmaf(F1, a1, F2 * (t2 - a2)) * rz;
      }
    }
  }
}

extern "C" void kernel_launch(void* const* d_in, const int* in_sizes, int n_in,
                              void* d_out, int out_size, void* d_ws, size_t ws_size,
                              hipStream_t stream){
  const float* x = (const float*)d_in[0];   // f32 (4096x1024)
  const float* w = (const float*)d_in[1];   // f32 (2048)
  float* out = (float*)d_out;               // f32 (4096x1024)
  (void)in_sizes; (void)n_in; (void)out_size; (void)d_ws; (void)ws_size;

  static void* sync_addr = nullptr;
  if (!sync_addr) (void)hipGetSymbolAddress(&sync_addr, HIP_SYMBOL(g_sync));
  (void)hipMemsetAsync(sync_addr, 0, (GRID * 4 + 4) * sizeof(int), stream);
  k_all<<<dim3(GRID), dim3(256), 0, stream>>>(x, w, out);
}